// Round 9
// baseline (58.487 us; speedup 1.0000x reference)
//
#include <hip/hip_runtime.h>
#include <math.h>
#include <stdint.h>

#define BIMG 32
#define QN 900
#define CN 80
#define NCAND 72000
#define NF4 18000
#define MAXDET 100
#define CAP 2048
#define PREF 2.0f          // prefilter: only L>=2 can ever be examined (validated r3-r8)
#define SEGCAP 280
#define NSEG 8
#define GATHCAP (NSEG * SEGCAP)   // 2240
#define TIERN 128u
#define TOPCAP 192
#define SORTN 256

typedef unsigned long long u64;
typedef uint32_t u32;

// ---- ws layout (written unconditionally every call; no pre-zero) ----
#define WS_GCNT   0                          // u32[256]
#define WS_BADBM  1024                       // u32[256][4]
#define WS_GSEG   5120                       // u64[256][SEGCAP]
#define WS_NEEDED (5120 + 256 * SEGCAP * 8)  // 578,560 B

__device__ __forceinline__ u32 fkey(float f) {
    u32 u = __float_as_uint(f);
    return (u & 0x80000000u) ? ~u : (u | 0x80000000u);
}
__device__ __forceinline__ float fkey_inv(u32 k) {
    u32 u = (k & 0x80000000u) ? (k ^ 0x80000000u) : ~k;
    return __uint_as_float(u);
}
__device__ __forceinline__ float rlanef(float v, int l) {
    return __int_as_float(__builtin_amdgcn_readlane(__float_as_int(v), l));
}

// ================= Kernel A: segment scan (256 blocks x 256 thr) =================
__global__ __launch_bounds__(256)
void k_scan(const float* __restrict__ logits, u32* __restrict__ badbm,
            u32* __restrict__ gcnt, u64* __restrict__ gseg)
{
    __shared__ u64 s_seg[SEGCAP];
    __shared__ u32 s_cnt;
    __shared__ u32 s_badbm[4];
    const int tid = threadIdx.x;
    const int img = blockIdx.x >> 3;
    const int seg = blockIdx.x & 7;
    const u32 qbase = (u32)(seg * 9000) / CN;
    if (tid == 0) s_cnt = 0u;
    if (tid < 4) s_badbm[tid] = 0u;
    __syncthreads();

    const float4* lg4 = (const float4*)(logits + (size_t)img * NCAND + (size_t)seg * 9000);
    float4 va[9];
    #pragma unroll
    for (int i = 0; i < 9; ++i) {
        int f4 = tid + i * 256;
        va[i] = lg4[(f4 < 2250) ? f4 : 0];
    }
    int kc = 0;
    #pragma unroll
    for (int i = 0; i < 9; ++i) {
        int f4 = tid + i * 256;
        bool inb = f4 < 2250;
        float4 vv = va[i];
        int ebase = seg * 9000 + f4 * 4;
        bool bad = inb && (!isfinite(vv.x) || !isfinite(vv.y) || !isfinite(vv.z) || !isfinite(vv.w));
        if (__any((int)bad)) {
            if (bad) {
                float c4[4] = {vv.x, vv.y, vv.z, vv.w};
                #pragma unroll
                for (int s2 = 0; s2 < 4; ++s2) {
                    if (!isfinite(c4[s2])) {
                        u32 q = (u32)(ebase + s2) / CN;
                        u32 lq = q - qbase;
                        atomicOr(&s_badbm[lq >> 5], 1u << (lq & 31));
                    }
                }
            }
        }
        if (inb) kc += (vv.x >= PREF) + (vv.y >= PREF) + (vv.z >= PREF) + (vv.w >= PREF);
    }
    u32 w = kc ? atomicAdd(&s_cnt, (u32)kc) : 0u;
    #pragma unroll
    for (int i = 0; i < 9; ++i) {
        int f4 = tid + i * 256;
        bool inb = f4 < 2250;
        float4 vv = va[i];
        int ebase = seg * 9000 + f4 * 4;
        float Ls[4] = {vv.x, vv.y, vv.z, vv.w};
        #pragma unroll
        for (int s2 = 0; s2 < 4; ++s2) {
            if (inb && Ls[s2] >= PREF) {
                if (w < SEGCAP) {
                    u32 i_img = (u32)(ebase + s2);
                    s_seg[w] = ((u64)fkey(Ls[s2]) << 32) | (u64)(~i_img);
                }
                ++w;
            }
        }
    }
    __syncthreads();
    u32 c = s_cnt; if (c > SEGCAP) c = SEGCAP;
    if (tid == 0) gcnt[img * NSEG + seg] = c;
    if (tid < 4) badbm[(img * NSEG + seg) * 4 + tid] = s_badbm[tid];
    for (u32 k = (u32)tid; k < c; k += 256u)
        gseg[(size_t)(img * NSEG + seg) * SEGCAP + k] = s_seg[k];
}

// ====== Kernel B: SINGLE WAVE per image — gather/select/sort/NMS/output ======
#define CEd(a, b, d) { if ((d) ? ((a) < (b)) : ((a) > (b))) { u64 t_ = (a); (a) = (b); (b) = t_; } }
#define SHFLS(kk) { \
    bool dblk = ((t4 & (kk)) == 0u); \
    for (u32 j = (kk) >> 1; j >= 4u; j >>= 1u) { \
        bool tm = dblk != ((t4 & j) != 0u); \
        int ls = (int)(j >> 2); \
        u64 p; \
        p = __shfl_xor(v0, ls, 64); v0 = (tm == (p > v0)) ? p : v0; \
        p = __shfl_xor(v1, ls, 64); v1 = (tm == (p > v1)) ? p : v1; \
        p = __shfl_xor(v2, ls, 64); v2 = (tm == (p > v2)) ? p : v2; \
        p = __shfl_xor(v3, ls, 64); v3 = (tm == (p > v3)) ? p : v3; \
    } \
    CEd(v0, v2, dblk); CEd(v1, v3, dblk); \
    CEd(v0, v1, dblk); CEd(v2, v3, dblk); }

__global__ __launch_bounds__(64)
void k_main(const float* __restrict__ boxes, const int* __restrict__ tsizes,
            const u32* __restrict__ badbm, const u32* __restrict__ gcnt,
            const u64* __restrict__ gseg, float* __restrict__ out)
{
    __shared__ float4  s_xy[QN];          // 14.4 KB
    __shared__ u64     s_ent[GATHCAP];    // 17.9 KB
    __shared__ u64     s_list[SORTN];     // 2 KB
    __shared__ u32     s_hist[512];       // 2 KB
    __shared__ u32     s_inv[32];
    __shared__ u32     s_sc[2];           // kthr, cumB handoff
    __shared__ float   s_ax1[MAXDET], s_ay1[MAXDET], s_ax2[MAXDET], s_ay2[MAXDET], s_aar[MAXDET];
    __shared__ u64     s_accPK[MAXDET];

    const int b = blockIdx.x;
    const int lane = threadIdx.x;         // 0..63, single wave
    const u64 ltm = (1ull << lane) - 1ull;

    if (lane < 32) s_inv[lane] = 0u;
    #pragma unroll
    for (int i = 0; i < 8; ++i) s_hist[lane * 8 + i] = 0u;
    __syncthreads();

    // ---- per-segment bad bitmaps -> image bitmap ----
    if (lane < 32) {
        int seg = lane >> 2, w = lane & 3;
        u32 val = badbm[(b * NSEG + seg) * 4 + w];
        if (val) {
            u32 qb = (u32)(seg * 9000) / CN;
            u32 qb5 = qb & 31u, bw = (qb >> 5) + (u32)w;
            atomicOr(&s_inv[bw], val << qb5);
            if (qb5) atomicOr(&s_inv[bw + 1], val >> (32u - qb5));
        }
    }

    // ---- boxes -> xyxy (prefetched), finiteness, off-max ----
    float4 va[15];
    #pragma unroll
    for (int i = 0; i < 15; ++i) {
        int q = lane + i * 64;
        va[i] = *(const float4*)(boxes + ((size_t)b * QN + ((q < QN) ? q : (QN - 1))) * 4);
    }
    u32 mk = 0u;
    #pragma unroll
    for (int i = 0; i < 15; ++i) {
        int q = lane + i * 64;
        if (q < QN) {
            float4 bx = va[i];
            float hw = 0.5f * bx.z, hh = 0.5f * bx.w;
            float x1 = bx.x - hw, y1 = bx.y - hh, x2 = bx.x + hw, y2 = bx.y + hh;
            s_xy[q] = make_float4(x1, y1, x2, y2);
            bool bf = isfinite(x1) && isfinite(y1) && isfinite(x2) && isfinite(y2);
            if (!bf) atomicOr(&s_inv[q >> 5], 1u << (q & 31));
            u32 k = fkey(isfinite(x1) ? x1 : 0.0f);
            k = max(k, fkey(isfinite(y1) ? y1 : 0.0f));
            k = max(k, fkey(isfinite(x2) ? x2 : 0.0f));
            k = max(k, fkey(isfinite(y2) ? y2 : 0.0f));
            mk = max(mk, k);
        }
    }
    #pragma unroll
    for (int d = 32; d > 0; d >>= 1) mk = max(mk, (u32)__shfl_xor((int)mk, d, 64));
    const float off = fkey_inv(mk) + 1.0f;
    __syncthreads();

    // ---- gather + filter (ballot-prefix, no atomics) + histogram ----
    u32 cnt = 0u;
    for (int s = 0; s < NSEG; ++s) {
        u32 c = gcnt[b * NSEG + s]; if (c > SEGCAP) c = SEGCAP;
        const u64* sp = gseg + (size_t)(b * NSEG + s) * SEGCAP;
        for (u32 k0 = 0; k0 < c; k0 += 64u) {
            u32 k = k0 + (u32)lane;
            bool inb = k < c;
            u64 e = inb ? sp[k] : 0ull;
            u32 q = (~((u32)e)) / CN;
            bool keep = inb && (((s_inv[q >> 5] >> (q & 31)) & 1u) == 0u);
            u64 mask = __ballot((int)keep);
            if (keep) {
                u32 pos = cnt + (u32)__popcll(mask & ltm);
                s_ent[pos] = e;
                u32 bin = ((u32)(e >> 32) - 0xC0000000u) >> 15;
                if (bin > 511u) bin = 511u;
                atomicAdd(&s_hist[bin], 1u);
            }
            cnt += (u32)__popcll(mask);
        }
    }
    const u32 total = cnt;
    __syncthreads();

    // ---- suffix-scan 512 bins, fully in registers ----
    u32 sfx[8];
    {
        u32 t = 0u;
        #pragma unroll
        for (int i = 7; i >= 0; --i) { t += s_hist[lane * 8 + i]; sfx[i] = t; }
        u32 h = t;
        #pragma unroll
        for (int d = 1; d < 64; d <<= 1) {
            u32 o = (u32)__shfl((int)h, (lane + d) & 63, 64);
            h += (lane + d < 64) ? o : 0u;
        }
        u32 excl = h - t;                  // suffix over lanes above = suffix(B_last+1)
        #pragma unroll
        for (int i = 0; i < 8; ++i) sfx[i] += excl;
        sfx[0] = sfx[0];                   // sfx[i] = global suffix at bin lane*8+i
        // stash excl in sfx-slot trick: keep separately
        // (use register below)
        #pragma unroll
        for (int i = 0; i < 8; ++i) s_hist[lane * 8 + i] = sfx[i];   // (unused later; kept for safety)
        // store excl for selection boundary:
        // handled via local variable below
        __syncthreads();
        // selection uses sfx[] and excl directly
        // (re-derive excl): excl = sfx-of-next-lane start
        // keep in a register:
        // NOTE: excl == (lane==63)?0:... already computed above
        // We persist it:
        // (fallthrough)
        // --- tier loop ---
        u32 excl_reg = excl;
        u32 cum_prev = 0u, kthr_prev = 0xFFFFFFFFu;
        int nacc = 0;
        while (true) {
            if (lane == 0) { s_sc[0] = 0xC0000000u; s_sc[1] = total; }
            __syncthreads();
            u32 T = cum_prev + TIERN;
            #pragma unroll
            for (int i = 0; i < 8; ++i) {
                u32 sB = sfx[i];
                u32 sB1 = (i < 7) ? sfx[i + 1] : excl_reg;
                if (sB >= T && sB1 < T) {
                    s_sc[0] = 0xC0000000u + (((u32)lane * 8u + (u32)i) << 15);
                    s_sc[1] = sB;
                }
            }
            __syncthreads();
            u32 kthr = s_sc[0], cumB = s_sc[1];
            if (cumB - cum_prev > (u32)TOPCAP) {       // tie overflow: single next bin
                if (lane == 0) { s_sc[0] = 0xC0000000u; s_sc[1] = total; }
                __syncthreads();
                u32 T2 = cum_prev + 1u;
                #pragma unroll
                for (int i = 0; i < 8; ++i) {
                    u32 sB = sfx[i];
                    u32 sB1 = (i < 7) ? sfx[i + 1] : excl_reg;
                    if (sB >= T2 && sB1 < T2) {
                        s_sc[0] = 0xC0000000u + (((u32)lane * 8u + (u32)i) << 15);
                        s_sc[1] = sB;
                    }
                }
                __syncthreads();
                kthr = s_sc[0]; cumB = s_sc[1];
            }

            // ---- compact tier into sort buffer (ballot-prefix) ----
            #pragma unroll
            for (int i = 0; i < 4; ++i) s_list[lane * 4 + i] = 0ull;
            __syncthreads();
            u32 tc = 0u;
            for (u32 k0 = 0; k0 < total; k0 += 64u) {
                u32 k = k0 + (u32)lane;
                bool inb = k < total;
                u64 e = inb ? s_ent[k] : 0ull;
                u32 key = (u32)(e >> 32);
                bool keep = inb && key >= kthr && key < kthr_prev;
                u64 mask = __ballot((int)keep);
                if (keep) {
                    u32 pos = tc + (u32)__popcll(mask & ltm);
                    if (pos < (u32)SORTN) s_list[pos] = e;
                }
                tc += (u32)__popcll(mask);
            }
            if (tc > (u32)SORTN) tc = (u32)SORTN;
            __syncthreads();

            // ---- bitonic sort descending: 256 elems, in-register (4/lane) ----
            {
                u32 t4 = (u32)lane << 2;
                u64 v0 = s_list[t4], v1 = s_list[t4 + 1], v2 = s_list[t4 + 2], v3 = s_list[t4 + 3];
                CEd(v0, v1, true); CEd(v2, v3, false);
                { bool d = ((t4 & 4u) == 0u);
                  CEd(v0, v2, d); CEd(v1, v3, d); CEd(v0, v1, d); CEd(v2, v3, d); }
                SHFLS(8u) SHFLS(16u) SHFLS(32u) SHFLS(64u) SHFLS(128u) SHFLS(256u)
                s_list[t4] = v0; s_list[t4 + 1] = v1; s_list[t4 + 2] = v2; s_list[t4 + 3] = v3;
            }
            __syncthreads();

            // ---- greedy NMS: on-demand suppression rows, readlane broadcasts ----
            for (u32 e0 = 0; e0 < tc && nacc < MAXDET; e0 += 64u) {
                u32 e = e0 + (u32)lane;
                bool valid = e < tc;
                u64 pk = valid ? s_list[e] : 0ull;
                float x1 = 0.f, y1 = 0.f, x2 = 0.f, y2 = 0.f, ar = 0.f;
                if (valid) {
                    u32 idx = ~((u32)pk);
                    u32 qq = idx / CN, cc = idx - qq * CN;
                    float ofc = (float)cc * off;
                    float4 xy = s_xy[qq];
                    x1 = xy.x + ofc; y1 = xy.y + ofc; x2 = xy.z + ofc; y2 = xy.w + ofc;
                    ar = fmaxf(x2 - x1, 0.0f) * fmaxf(y2 - y1, 0.0f);
                }
                // vs already-accepted (uniform-address LDS broadcast reads)
                bool sup = false;
                for (int a = 0; a < nacc; ++a) {
                    float ax1 = s_ax1[a], ay1 = s_ay1[a], ax2 = s_ax2[a], ay2 = s_ay2[a];
                    float ltx = fmaxf(ax1, x1), lty = fmaxf(ay1, y1);
                    float rbx = fminf(ax2, x2), rby = fminf(ay2, y2);
                    float inter = fmaxf(rbx - ltx, 0.0f) * fmaxf(rby - lty, 0.0f);
                    float uni = s_aar[a] + ar - inter;   // area(sel)+area(cand)-inter (ref)
                    sup = sup || ((inter / fmaxf(uni, 1e-9f)) > 0.5f);
                }
                u64 sup_run = __ballot((int)(sup && valid));
                int cnt_rem = (int)((tc - e0 < 64u) ? (tc - e0) : 64u);
                int nacc0 = nacc;
                u64 amask = 0ull;
                for (int el = 0; el < cnt_rem; ++el) {   // uniform serial walk
                    if (nacc >= MAXDET) break;
                    if (!((sup_run >> el) & 1ull)) {
                        amask |= (1ull << el);
                        ++nacc;
                        // accepted el suppresses later candidates: on-demand row
                        float bx1 = rlanef(x1, el), by1 = rlanef(y1, el);
                        float bx2 = rlanef(x2, el), by2 = rlanef(y2, el);
                        float bar = rlanef(ar, el);
                        float ltx = fmaxf(bx1, x1), lty = fmaxf(by1, y1);
                        float rbx = fminf(bx2, x2), rby = fminf(by2, y2);
                        float inter = fmaxf(rbx - ltx, 0.0f) * fmaxf(rby - lty, 0.0f);
                        float uni = bar + ar - inter;    // selected first (ref order)
                        bool sp = (inter / fmaxf(uni, 1e-9f)) > 0.5f;
                        sup_run |= __ballot((int)sp);
                    }
                }
                if ((amask >> lane) & 1ull) {
                    int slot = nacc0 + (int)__popcll(amask & ltm);
                    s_ax1[slot] = x1; s_ay1[slot] = y1;
                    s_ax2[slot] = x2; s_ay2[slot] = y2;
                    s_aar[slot] = ar;
                    s_accPK[slot] = pk;
                }
                __syncthreads();
            }

            cum_prev = cumB; kthr_prev = kthr;
            if (nacc >= MAXDET || cum_prev >= total) break;
        }

        // ---- outputs: [scs][lab][boxes][goods], f32 ----
        __syncthreads();
        const int* ts = tsizes + b * 2;
        float th = (float)ts[0], tw = (float)ts[1];   // (h, w)
        for (int d = lane; d < MAXDET; d += 64) {
            bool good = d < nacc;
            float sc = 0.0f, lb = -1.0f, gd = 0.0f;
            float ox1 = 0.f, oy1 = 0.f, ox2 = 0.f, oy2 = 0.f;
            if (good) {
                u64 pk = s_accPK[d];
                u32 key = (u32)(pk >> 32);
                u32 idx = ~((u32)pk);
                u32 qq = idx / CN, cc = idx - qq * CN;
                float L = fkey_inv(key);
                sc = 1.0f / (1.0f + expf(-L));
                lb = (float)cc;
                gd = 1.0f;
                ox1 = s_xy[qq].x * tw;
                oy1 = s_xy[qq].y * th;
                ox2 = s_xy[qq].z * tw;
                oy2 = s_xy[qq].w * th;
            }
            out[b * MAXDET + d] = sc;
            out[BIMG * MAXDET + b * MAXDET + d] = lb;
            float* ob = out + 2 * BIMG * MAXDET + (size_t)(b * MAXDET + d) * 4;
            ob[0] = ox1; ob[1] = oy1; ob[2] = ox2; ob[3] = oy2;
            out[2 * BIMG * MAXDET + BIMG * MAXDET * 4 + b * MAXDET + d] = gd;
        }
    }
}

// ================= Fallback: validated round-4 single kernel =================
#define NTHREADS 1024
__device__ __forceinline__ void scan6(const float4* v, int itbase, int tid, int lane,
                                      uint8_t* s_finq, u64* s_list, u32* s_cnt)
{
    #pragma unroll
    for (int j = 0; j < 6; ++j) {
        int i4 = tid + (itbase + j) * NTHREADS;
        bool inb = i4 < NF4;
        float4 vv = v[j];
        int i0 = i4 * 4;
        bool bad = inb && (!isfinite(vv.x) || !isfinite(vv.y) || !isfinite(vv.z) || !isfinite(vv.w));
        if (__any((int)bad)) {
            if (inb) {
                if (!isfinite(vv.x)) s_finq[(i0 + 0) / CN] = 0;
                if (!isfinite(vv.y)) s_finq[(i0 + 1) / CN] = 0;
                if (!isfinite(vv.z)) s_finq[(i0 + 2) / CN] = 0;
                if (!isfinite(vv.w)) s_finq[(i0 + 3) / CN] = 0;
            }
        }
        float Ls[4] = {vv.x, vv.y, vv.z, vv.w};
        #pragma unroll
        for (int s = 0; s < 4; ++s) {
            bool p = inb && (Ls[s] >= PREF);
            u64 mask = __ballot((int)p);
            if (mask) {
                int leader = __ffsll((long long)mask) - 1;
                u32 base = 0;
                if (lane == leader) base = atomicAdd(s_cnt, (u32)__popcll(mask));
                base = (u32)__shfl((int)base, leader, 64);
                if (p) {
                    u32 pos = base + (u32)__popcll(mask & ((1ull << lane) - 1ull));
                    if (pos < CAP) {
                        u32 i = (u32)(i0 + s);
                        s_list[pos] = ((u64)fkey(Ls[s]) << 32) | (u64)(~i);
                    }
                }
            }
        }
    }
}

__global__ __launch_bounds__(NTHREADS)
void ov_post(const float* __restrict__ logits, const float* __restrict__ boxes,
             const int* __restrict__ tsizes, float* __restrict__ out)
{
    __shared__ float   s_xyxy[QN][4];
    __shared__ uint8_t s_finq[QN];
    __shared__ u64     s_list[CAP];
    __shared__ u32     s_offk;
    __shared__ u32     s_cnt;
    __shared__ u64     s_mat[64];
    __shared__ u64     s_wsup[16];
    __shared__ u64     s_vmask;
    __shared__ float   s_ax1[MAXDET], s_ay1[MAXDET], s_ax2[MAXDET], s_ay2[MAXDET], s_aar[MAXDET];
    __shared__ u32     s_accE[MAXDET];
    __shared__ int     s_nacc;
    __shared__ int     s_done;

    const int b = blockIdx.x;
    const int tid = threadIdx.x;
    const int lane = tid & 63;
    const int wv = tid >> 6;
    const float* lg = logits + (size_t)b * NCAND;
    const float4* lg4 = (const float4*)lg;

    if (tid == 0) { s_offk = 0u; s_cnt = 0u; s_nacc = 0; s_done = 0; }
    __syncthreads();

    if (tid < QN) {
        float4 bx = *(const float4*)(boxes + ((size_t)b * QN + tid) * 4);
        float hw = 0.5f * bx.z, hh = 0.5f * bx.w;
        float x1 = bx.x - hw, y1 = bx.y - hh, x2 = bx.x + hw, y2 = bx.y + hh;
        s_xyxy[tid][0] = x1; s_xyxy[tid][1] = y1;
        s_xyxy[tid][2] = x2; s_xyxy[tid][3] = y2;
        s_finq[tid] = (isfinite(x1) && isfinite(y1) && isfinite(x2) && isfinite(y2)) ? 1 : 0;
        u32 k = fkey(isfinite(x1) ? x1 : 0.0f);
        k = max(k, fkey(isfinite(y1) ? y1 : 0.0f));
        k = max(k, fkey(isfinite(x2) ? x2 : 0.0f));
        k = max(k, fkey(isfinite(y2) ? y2 : 0.0f));
        atomicMax(&s_offk, k);
    }
    __syncthreads();

    {
        float4 vA[6], vB[6];
        #pragma unroll
        for (int j = 0; j < 6; ++j) vA[j] = lg4[tid + j * NTHREADS];
        #pragma unroll
        for (int j = 0; j < 6; ++j) vB[j] = lg4[tid + (6 + j) * NTHREADS];
        scan6(vA, 0, tid, lane, s_finq, s_list, &s_cnt);
        #pragma unroll
        for (int j = 0; j < 6; ++j) {
            int i4 = tid + (12 + j) * NTHREADS;
            vA[j] = lg4[(i4 < NF4) ? i4 : (NF4 - 1)];
        }
        scan6(vB, 6, tid, lane, s_finq, s_list, &s_cnt);
        scan6(vA, 12, tid, lane, s_finq, s_list, &s_cnt);
    }
    __syncthreads();

    u32 n = s_cnt; if (n > CAP) n = CAP;
    for (int t = tid; t < CAP; t += NTHREADS) {
        if (t < (int)n) {
            u32 idx = ~((u32)s_list[t]);
            if (!s_finq[idx / CN]) s_list[t] = 0ull;
        } else {
            s_list[t] = 0ull;
        }
    }
    __syncthreads();

    {
        u64 v0 = s_list[tid], v1 = s_list[tid + 1024];
        for (u32 k = 2; k <= 64; k <<= 1)
            for (u32 j = k >> 1; j > 0; j >>= 1) {
                { u64 p = __shfl_xor(v0, (int)j, 64); u32 e = (u32)tid;
                  bool tm = (((e & k) == 0) != ((e & j) != 0)); v0 = (tm == (p > v0)) ? p : v0; }
                { u64 p = __shfl_xor(v1, (int)j, 64); u32 e = (u32)tid + 1024u;
                  bool tm = (((e & k) == 0) != ((e & j) != 0)); v1 = (tm == (p > v1)) ? p : v1; }
            }
        s_list[tid] = v0; s_list[tid + 1024] = v1;
        __syncthreads();
        for (u32 k = 128; k <= 2048; k <<= 1) {
            for (u32 j = k >> 1; j >= 64; j >>= 1) {
                for (u32 t = (u32)tid; t < CAP; t += NTHREADS) {
                    u32 ixj = t ^ j;
                    if (ixj > t) {
                        u64 a = s_list[t], c = s_list[ixj];
                        bool sw = ((t & k) == 0) ? (a < c) : (a > c);
                        if (sw) { s_list[t] = c; s_list[ixj] = a; }
                    }
                }
                __syncthreads();
            }
            v0 = s_list[tid]; v1 = s_list[tid + 1024];
            for (u32 j = 32; j > 0; j >>= 1) {
                { u64 p = __shfl_xor(v0, (int)j, 64); u32 e = (u32)tid;
                  bool tm = (((e & k) == 0) != ((e & j) != 0)); v0 = (tm == (p > v0)) ? p : v0; }
                { u64 p = __shfl_xor(v1, (int)j, 64); u32 e = (u32)tid + 1024u;
                  bool tm = (((e & k) == 0) != ((e & j) != 0)); v1 = (tm == (p > v1)) ? p : v1; }
            }
            s_list[tid] = v0; s_list[tid + 1024] = v1;
            __syncthreads();
        }
    }

    const float off = fkey_inv(s_offk) + 1.0f;
    for (u32 e0 = 0; e0 < n; e0 += 64) {
        u32 e = e0 + (u32)lane;
        u64 pk = (e < n) ? s_list[e] : 0ull;
        bool valid = (pk != 0ull);
        float x1 = 0.f, y1 = 0.f, x2 = 0.f, y2 = 0.f, ar = 0.f;
        if (valid) {
            u32 idx = ~((u32)pk);
            u32 qq = idx / CN, cc = idx - qq * CN;
            float ofc = (float)cc * off;
            x1 = s_xyxy[qq][0] + ofc; y1 = s_xyxy[qq][1] + ofc;
            x2 = s_xyxy[qq][2] + ofc; y2 = s_xyxy[qq][3] + ofc;
            ar = fmaxf(x2 - x1, 0.0f) * fmaxf(y2 - y1, 0.0f);
        }
        #pragma unroll
        for (int rr = 0; rr < 4; ++rr) {
            int r = (wv << 2) | rr;
            float rx1 = __shfl(x1, r, 64), ry1 = __shfl(y1, r, 64);
            float rx2 = __shfl(x2, r, 64), ry2 = __shfl(y2, r, 64);
            float rar = __shfl(ar, r, 64);
            float ltx = fmaxf(rx1, x1), lty = fmaxf(ry1, y1);
            float rbx = fminf(rx2, x2), rby = fminf(ry2, y2);
            float inter = fmaxf(rbx - ltx, 0.0f) * fmaxf(rby - lty, 0.0f);
            float uni = rar + ar - inter;
            bool s = valid && ((inter / fmaxf(uni, 1e-9f)) > 0.5f);
            u64 rm = __ballot((int)s);
            if (lane == 0) s_mat[r] = rm;
        }
        int nacc0 = s_nacc;
        bool sup = false;
        for (int a = wv; a < nacc0; a += 16) {
            float ltx = fmaxf(s_ax1[a], x1), lty = fmaxf(s_ay1[a], y1);
            float rbx = fminf(s_ax2[a], x2), rby = fminf(s_ay2[a], y2);
            float inter = fmaxf(rbx - ltx, 0.0f) * fmaxf(rby - lty, 0.0f);
            float uni = s_aar[a] + ar - inter;
            sup = sup || ((inter / fmaxf(uni, 1e-9f)) > 0.5f);
        }
        u64 wm = __ballot((int)(sup && valid));
        if (lane == 0) s_wsup[wv] = wm;
        u64 vmm = __ballot((int)valid);
        if (tid == 0) s_vmask = vmm;
        __syncthreads();

        if (wv == 0) {
            u64 m = s_mat[lane];
            u64 t = (lane < 16) ? s_wsup[lane] : 0ull;
            t |= __shfl_xor(t, 8, 64);
            t |= __shfl_xor(t, 4, 64);
            t |= __shfl_xor(t, 2, 64);
            t |= __shfl_xor(t, 1, 64);
            u64 sup_run = __shfl(t, 0, 64);
            u64 vm = s_vmask;
            int cnt_rem = (int)((n - e0 < 64u) ? (n - e0) : 64u);
            u64 full = (cnt_rem >= 64) ? ~0ull : ((1ull << cnt_rem) - 1ull);
            bool exhausted = ((vm & full) != full) || (e0 + 64 >= n);
            int nacc = nacc0;
            u64 amask = 0ull;
            for (int el = 0; el < cnt_rem; ++el) {
                if (nacc >= MAXDET) break;
                if (!((vm >> el) & 1ull)) break;
                if (!((sup_run >> el) & 1ull)) {
                    amask |= (1ull << el);
                    sup_run |= __shfl(m, el, 64);
                    ++nacc;
                }
            }
            if ((amask >> lane) & 1ull) {
                int slot = nacc0 + (int)__popcll(amask & ((1ull << lane) - 1ull));
                s_ax1[slot] = x1; s_ay1[slot] = y1;
                s_ax2[slot] = x2; s_ay2[slot] = y2;
                s_aar[slot] = ar;
                s_accE[slot] = e;
            }
            if (lane == 0) {
                s_nacc = nacc;
                if (nacc >= MAXDET || exhausted) s_done = 1;
            }
        }
        __syncthreads();
        if (s_done) break;
    }

    if (tid < MAXDET) {
        const int* ts = tsizes + b * 2;
        float th = (float)ts[0], tw = (float)ts[1];
        int d = tid;
        bool good = d < s_nacc;
        float sc = 0.0f, lb = -1.0f, gd = 0.0f;
        float ox1 = 0.f, oy1 = 0.f, ox2 = 0.f, oy2 = 0.f;
        if (good) {
            u64 pk = s_list[s_accE[d]];
            u32 key = (u32)(pk >> 32);
            u32 idx = ~((u32)pk);
            u32 qq = idx / CN, cc = idx - qq * CN;
            float L = fkey_inv(key);
            sc = 1.0f / (1.0f + expf(-L));
            lb = (float)cc;
            gd = 1.0f;
            ox1 = s_xyxy[qq][0] * tw;
            oy1 = s_xyxy[qq][1] * th;
            ox2 = s_xyxy[qq][2] * tw;
            oy2 = s_xyxy[qq][3] * th;
        }
        out[b * MAXDET + d] = sc;
        out[BIMG * MAXDET + b * MAXDET + d] = lb;
        float* ob = out + 2 * BIMG * MAXDET + (size_t)(b * MAXDET + d) * 4;
        ob[0] = ox1; ob[1] = oy1; ob[2] = ox2; ob[3] = oy2;
        out[2 * BIMG * MAXDET + BIMG * MAXDET * 4 + b * MAXDET + d] = gd;
    }
}

extern "C" void kernel_launch(void* const* d_in, const int* in_sizes, int n_in,
                              void* d_out, int out_size, void* d_ws, size_t ws_size,
                              hipStream_t stream) {
    (void)in_sizes; (void)n_in; (void)out_size;
    const float* logits = (const float*)d_in[0];
    const float* boxes  = (const float*)d_in[1];
    const int*   tsizes = (const int*)d_in[2];
    float* out = (float*)d_out;

    if (ws_size >= (size_t)WS_NEEDED) {
        char* ws = (char*)d_ws;
        u32* gcnt  = (u32*)(ws + WS_GCNT);
        u32* badbm = (u32*)(ws + WS_BADBM);
        u64* gseg  = (u64*)(ws + WS_GSEG);
        k_scan<<<BIMG * NSEG, 256, 0, stream>>>(logits, badbm, gcnt, gseg);
        k_main<<<BIMG, 64, 0, stream>>>(boxes, tsizes, badbm, gcnt, gseg, out);
    } else {
        ov_post<<<BIMG, NTHREADS, 0, stream>>>(logits, boxes, tsizes, out);
    }
}

// Round 10
// 39.275 us; speedup vs baseline: 1.4892x; 1.4892x over previous
//
#include <hip/hip_runtime.h>
#include <math.h>
#include <stdint.h>

#define BIMG 32
#define QN 900
#define CN 80
#define NCAND 72000
#define NF4 18000
#define MAXDET 100
#define CAP 2048
#define PREF 2.0f          // prefilter: only L>=2 can ever be examined (validated r3-r9)
#define SEGCAP 280
#define NSEG 8
#define GATHCAP (NSEG * SEGCAP)   // 2240
#define TIERN 128u
#define TOPCAP 192
#define SORTN 256

typedef unsigned long long u64;
typedef uint32_t u32;

// ---- ws layout (written unconditionally every call; no pre-zero) ----
#define WS_GCNT   0                          // u32[256]
#define WS_BADBM  1024                       // u32[256][4]
#define WS_GSEG   5120                       // u64[256][SEGCAP]
#define WS_NEEDED (5120 + 256 * SEGCAP * 8)  // 578,560 B

__device__ __forceinline__ u32 fkey(float f) {
    u32 u = __float_as_uint(f);
    return (u & 0x80000000u) ? ~u : (u | 0x80000000u);
}
__device__ __forceinline__ float fkey_inv(u32 k) {
    u32 u = (k & 0x80000000u) ? (k ^ 0x80000000u) : ~k;
    return __uint_as_float(u);
}

// ================= Kernel A: segment scan (256 blocks x 256 thr) =================
__global__ __launch_bounds__(256)
void k_scan(const float* __restrict__ logits, u32* __restrict__ badbm,
            u32* __restrict__ gcnt, u64* __restrict__ gseg)
{
    __shared__ u64 s_seg[SEGCAP];
    __shared__ u32 s_cnt;
    __shared__ u32 s_badbm[4];
    const int tid = threadIdx.x;
    const int img = blockIdx.x >> 3;
    const int seg = blockIdx.x & 7;
    const u32 qbase = (u32)(seg * 9000) / CN;
    if (tid == 0) s_cnt = 0u;
    if (tid < 4) s_badbm[tid] = 0u;
    __syncthreads();

    const float4* lg4 = (const float4*)(logits + (size_t)img * NCAND + (size_t)seg * 9000);
    float4 va[9];
    #pragma unroll
    for (int i = 0; i < 9; ++i) {
        int f4 = tid + i * 256;
        va[i] = lg4[(f4 < 2250) ? f4 : 0];
    }
    int kc = 0;
    #pragma unroll
    for (int i = 0; i < 9; ++i) {
        int f4 = tid + i * 256;
        bool inb = f4 < 2250;
        float4 vv = va[i];
        int ebase = seg * 9000 + f4 * 4;
        bool bad = inb && (!isfinite(vv.x) || !isfinite(vv.y) || !isfinite(vv.z) || !isfinite(vv.w));
        if (__any((int)bad)) {
            if (bad) {
                float c4[4] = {vv.x, vv.y, vv.z, vv.w};
                #pragma unroll
                for (int s2 = 0; s2 < 4; ++s2) {
                    if (!isfinite(c4[s2])) {
                        u32 q = (u32)(ebase + s2) / CN;
                        u32 lq = q - qbase;
                        atomicOr(&s_badbm[lq >> 5], 1u << (lq & 31));
                    }
                }
            }
        }
        if (inb) kc += (vv.x >= PREF) + (vv.y >= PREF) + (vv.z >= PREF) + (vv.w >= PREF);
    }
    u32 w = kc ? atomicAdd(&s_cnt, (u32)kc) : 0u;
    #pragma unroll
    for (int i = 0; i < 9; ++i) {
        int f4 = tid + i * 256;
        bool inb = f4 < 2250;
        float4 vv = va[i];
        int ebase = seg * 9000 + f4 * 4;
        float Ls[4] = {vv.x, vv.y, vv.z, vv.w};
        #pragma unroll
        for (int s2 = 0; s2 < 4; ++s2) {
            if (inb && Ls[s2] >= PREF) {
                if (w < SEGCAP) {
                    u32 i_img = (u32)(ebase + s2);
                    s_seg[w] = ((u64)fkey(Ls[s2]) << 32) | (u64)(~i_img);
                }
                ++w;
            }
        }
    }
    __syncthreads();
    u32 c = s_cnt; if (c > SEGCAP) c = SEGCAP;
    if (tid == 0) gcnt[img * NSEG + seg] = c;
    if (tid < 4) badbm[(img * NSEG + seg) * 4 + tid] = s_badbm[tid];
    for (u32 k = (u32)tid; k < c; k += 256u)
        gseg[(size_t)(img * NSEG + seg) * SEGCAP + k] = s_seg[k];
}

// ====== Kernel B: gather(prefetched) + tiered select + wave-sort + NMS (512 thr) ======
#define CEd(a, b, d) { if ((d) ? ((a) < (b)) : ((a) > (b))) { u64 t_ = (a); (a) = (b); (b) = t_; } }
#define SHFLS(kk) { \
    bool dblk = ((t4 & (kk)) == 0u); \
    for (u32 j = (kk) >> 1; j >= 4u; j >>= 1u) { \
        bool tm = dblk != ((t4 & j) != 0u); \
        int ls = (int)(j >> 2); \
        u64 p; \
        p = __shfl_xor(v0, ls, 64); v0 = (tm == (p > v0)) ? p : v0; \
        p = __shfl_xor(v1, ls, 64); v1 = (tm == (p > v1)) ? p : v1; \
        p = __shfl_xor(v2, ls, 64); v2 = (tm == (p > v2)) ? p : v2; \
        p = __shfl_xor(v3, ls, 64); v3 = (tm == (p > v3)) ? p : v3; \
    } \
    CEd(v0, v2, dblk); CEd(v1, v3, dblk); \
    CEd(v0, v1, dblk); CEd(v2, v3, dblk); }

__global__ __launch_bounds__(512)
void k_main(const float* __restrict__ boxes, const int* __restrict__ tsizes,
            const u32* __restrict__ badbm, const u32* __restrict__ gcnt,
            const u64* __restrict__ gseg, float* __restrict__ out)
{
    __shared__ u64     s_ent[GATHCAP];    // 17.9 KB
    __shared__ float4  s_xy[QN];          // 14.4 KB
    __shared__ u64     s_list[SORTN];     // 2 KB
    __shared__ u32     s_hist[512];       // histogram -> suffix
    __shared__ u32     s_inv[32];
    __shared__ u32     s_segc[NSEG];
    __shared__ u32     s_wtot[8];
    __shared__ u32     s_offk, s_cnt, s_tc, s_kthr, s_cumB;
    __shared__ u64     s_mat[64];
    __shared__ u64     s_wsup[8];
    __shared__ float   s_ax1[MAXDET], s_ay1[MAXDET], s_ax2[MAXDET], s_ay2[MAXDET], s_aar[MAXDET];
    __shared__ u64     s_accPK[MAXDET];
    __shared__ int     s_nacc;

    const int b = blockIdx.x;
    const int tid = threadIdx.x;
    const int lane = tid & 63;
    const int wv = tid >> 6;

    // ---- prefetch: 5 fixed-address gseg slots/thread + this thread's boxes ----
    u64 ge[5];
    {
        const u64* gp = gseg + (size_t)b * GATHCAP;
        #pragma unroll
        for (int i = 0; i < 5; ++i) {
            u32 p = (u32)tid + (u32)i * 512u;
            ge[i] = gp[(p < (u32)GATHCAP) ? p : (u32)(GATHCAP - 1)];
        }
    }
    float4 bxa[2];
    #pragma unroll
    for (int i = 0; i < 2; ++i) {
        int q = tid + i * 512;
        bxa[i] = *(const float4*)(boxes + ((size_t)b * QN + ((q < QN) ? q : (QN - 1))) * 4);
    }

    if (tid == 0) { s_offk = 0u; s_cnt = 0u; s_nacc = 0; }
    if (tid < 32) s_inv[tid] = 0u;
    if (tid < NSEG) { u32 c = gcnt[b * NSEG + tid]; s_segc[tid] = (c < (u32)SEGCAP) ? c : (u32)SEGCAP; }
    s_hist[tid] = 0u;
    __syncthreads();

    // ---- per-segment bad bitmaps -> image bitmap ----
    if (lane < 4) {
        u32 val = badbm[(b * NSEG + wv) * 4 + lane];
        if (val) {
            u32 qb = (u32)(wv * 9000) / CN;
            u32 qb5 = qb & 31u, bw = (qb >> 5) + (u32)lane;
            atomicOr(&s_inv[bw], val << qb5);
            if (qb5) atomicOr(&s_inv[bw + 1], val >> (32u - qb5));
        }
    }
    // ---- boxes -> xyxy, finiteness, off-max ----
    u32 mk = 0u;
    #pragma unroll
    for (int i = 0; i < 2; ++i) {
        int q = tid + i * 512;
        if (q < QN) {
            float4 bx = bxa[i];
            float hw = 0.5f * bx.z, hh = 0.5f * bx.w;
            float x1 = bx.x - hw, y1 = bx.y - hh, x2 = bx.x + hw, y2 = bx.y + hh;
            s_xy[q] = make_float4(x1, y1, x2, y2);
            bool bf = isfinite(x1) && isfinite(y1) && isfinite(x2) && isfinite(y2);
            if (!bf) atomicOr(&s_inv[q >> 5], 1u << (q & 31));
            u32 k = fkey(isfinite(x1) ? x1 : 0.0f);
            k = max(k, fkey(isfinite(y1) ? y1 : 0.0f));
            k = max(k, fkey(isfinite(x2) ? x2 : 0.0f));
            k = max(k, fkey(isfinite(y2) ? y2 : 0.0f));
            mk = max(mk, k);
        }
    }
    #pragma unroll
    for (int d = 32; d > 0; d >>= 1) mk = max(mk, (u32)__shfl_xor((int)mk, d, 64));
    if (lane == 0) atomicMax(&s_offk, mk);
    __syncthreads();

    // ---- filter prefetched slots + two-pass compaction + histogram ----
    {
        bool gk[5]; int kc = 0;
        #pragma unroll
        for (int i = 0; i < 5; ++i) {
            gk[i] = false;
            u32 p = (u32)tid + (u32)i * 512u;
            if (p < (u32)GATHCAP) {
                u32 seg = p / (u32)SEGCAP;
                u32 k = p - seg * (u32)SEGCAP;
                if (k < s_segc[seg]) {
                    u32 q = (~((u32)ge[i])) / CN;
                    if (((s_inv[q >> 5] >> (q & 31)) & 1u) == 0u) { gk[i] = true; ++kc; }
                }
            }
        }
        u32 w = kc ? atomicAdd(&s_cnt, (u32)kc) : 0u;
        #pragma unroll
        for (int i = 0; i < 5; ++i) {
            if (gk[i]) {
                s_ent[w++] = ge[i];
                u32 bin = ((u32)(ge[i] >> 32) - 0xC0000000u) >> 15;
                if (bin > 511u) bin = 511u;
                atomicAdd(&s_hist[bin], 1u);
            }
        }
    }
    __syncthreads();

    // ---- suffix-scan 512 bins (wave shfl + cross-wave combine) ----
    {
        u32 h = s_hist[tid];
        #pragma unroll
        for (int d = 1; d < 64; d <<= 1) {
            u32 o = (u32)__shfl((int)h, (lane + d) & 63, 64);
            h += (lane + d < 64) ? o : 0u;
        }
        if (lane == 0) s_wtot[wv] = h;
        __syncthreads();
        u32 after = 0u;
        for (int w2 = wv + 1; w2 < 8; ++w2) after += s_wtot[w2];
        s_hist[tid] = h + after;
        __syncthreads();
    }
    const u32 total = s_cnt;
    const float off = fkey_inv(s_offk) + 1.0f;

    // ---- tier loop: select next-128-with-ties, sort 256 in wave 0, NMS ----
    u32 cum_prev = 0u, kthr_prev = 0xFFFFFFFFu;
    while (true) {
        if (tid == 0) { s_kthr = 0xC0000000u; s_cumB = total; s_tc = 0u; }
        __syncthreads();
        u32 T = cum_prev + TIERN;
        if (s_hist[tid] >= T && (tid == 511 || s_hist[tid + 1] < T)) {
            s_kthr = 0xC0000000u + ((u32)tid << 15); s_cumB = s_hist[tid];
        }
        __syncthreads();
        if (s_cumB - cum_prev > (u32)TOPCAP) {       // tie overflow: take single next bin
            if (tid == 0) { s_kthr = 0xC0000000u; s_cumB = total; }
            __syncthreads();
            u32 T2 = cum_prev + 1u;
            if (s_hist[tid] >= T2 && (tid == 511 || s_hist[tid + 1] < T2)) {
                s_kthr = 0xC0000000u + ((u32)tid << 15); s_cumB = s_hist[tid];
            }
            __syncthreads();
        }
        const u32 kthr = s_kthr, cumB = s_cumB;

        // compact tier entries (two-pass) + zero sort buffer
        if (tid < SORTN) s_list[tid] = 0ull;
        u64 te[5]; bool tk[5]; int tkc = 0;
        #pragma unroll
        for (int i = 0; i < 5; ++i) {
            tk[i] = false;
            u32 p = (u32)tid + (u32)i * 512u;
            if (p < total) {
                u64 e = s_ent[p];
                u32 key = (u32)(e >> 32);
                if (key >= kthr && key < kthr_prev) { tk[i] = true; te[i] = e; ++tkc; }
            }
        }
        u32 base = tkc ? atomicAdd(&s_tc, (u32)tkc) : 0u;
        __syncthreads();                              // zeros + counts done
        {
            u32 w = base;
            #pragma unroll
            for (int i = 0; i < 5; ++i) {
                if (tk[i]) { if (w < (u32)SORTN) s_list[w] = te[i]; ++w; }
            }
        }
        __syncthreads();
        u32 tc = s_tc; if (tc > (u32)SORTN) tc = (u32)SORTN;

        // ---- bitonic sort descending: 256 elems, wave 0 only, in-register ----
        if (wv == 0) {
            u32 t4 = (u32)lane << 2;
            u64 v0 = s_list[t4], v1 = s_list[t4 + 1], v2 = s_list[t4 + 2], v3 = s_list[t4 + 3];
            CEd(v0, v1, true); CEd(v2, v3, false);                                // k=2
            { bool d = ((t4 & 4u) == 0u);
              CEd(v0, v2, d); CEd(v1, v3, d); CEd(v0, v1, d); CEd(v2, v3, d); }   // k=4
            SHFLS(8u) SHFLS(16u) SHFLS(32u) SHFLS(64u) SHFLS(128u) SHFLS(256u)
            s_list[t4] = v0; s_list[t4 + 1] = v1; s_list[t4 + 2] = v2; s_list[t4 + 3] = v3;
        }
        __syncthreads();

        // ---- chunked-mask greedy NMS (exact; 8 waves; carried accepted set) ----
        for (u32 e0 = 0; e0 < tc; e0 += 64) {
            u32 e = e0 + (u32)lane;
            bool valid = e < tc;
            u64 pk = valid ? s_list[e] : 0ull;
            float x1 = 0.f, y1 = 0.f, x2 = 0.f, y2 = 0.f, ar = 0.f;
            if (valid) {
                u32 idx = ~((u32)pk);
                u32 qq = idx / CN, cc = idx - qq * CN;
                float ofc = (float)cc * off;
                float4 xy = s_xy[qq];
                x1 = xy.x + ofc; y1 = xy.y + ofc; x2 = xy.z + ofc; y2 = xy.w + ofc;
                ar = fmaxf(x2 - x1, 0.0f) * fmaxf(y2 - y1, 0.0f);
            }
            #pragma unroll
            for (int rr = 0; rr < 8; ++rr) {
                int r = (wv << 3) | rr;
                float rx1 = __shfl(x1, r, 64), ry1 = __shfl(y1, r, 64);
                float rx2 = __shfl(x2, r, 64), ry2 = __shfl(y2, r, 64);
                float rar = __shfl(ar, r, 64);
                float ltx = fmaxf(rx1, x1), lty = fmaxf(ry1, y1);
                float rbx = fminf(rx2, x2), rby = fminf(ry2, y2);
                float inter = fmaxf(rbx - ltx, 0.0f) * fmaxf(rby - lty, 0.0f);
                float uni = rar + ar - inter;         // area(sel)+area(cand)-inter (ref order)
                bool sp = valid && ((inter / fmaxf(uni, 1e-9f)) > 0.5f);
                u64 rm = __ballot((int)sp);
                if (lane == 0) s_mat[r] = rm;
            }
            int nacc0 = s_nacc;
            bool sup = false;
            for (int a = wv; a < nacc0; a += 8) {
                float ltx = fmaxf(s_ax1[a], x1), lty = fmaxf(s_ay1[a], y1);
                float rbx = fminf(s_ax2[a], x2), rby = fminf(s_ay2[a], y2);
                float inter = fmaxf(rbx - ltx, 0.0f) * fmaxf(rby - lty, 0.0f);
                float uni = s_aar[a] + ar - inter;
                sup = sup || ((inter / fmaxf(uni, 1e-9f)) > 0.5f);
            }
            u64 wm = __ballot((int)(sup && valid));
            if (lane == 0) s_wsup[wv] = wm;
            __syncthreads();

            if (wv == 0) {
                u64 m = s_mat[lane];
                u64 t = (lane < 8) ? s_wsup[lane] : 0ull;
                t |= __shfl_xor(t, 4, 64);
                t |= __shfl_xor(t, 2, 64);
                t |= __shfl_xor(t, 1, 64);
                u64 sup_run = __shfl(t, 0, 64);
                int cnt_rem = (int)((tc - e0 < 64u) ? (tc - e0) : 64u);
                int nacc = nacc0;
                u64 amask = 0ull;
                for (int el = 0; el < cnt_rem; ++el) {
                    if (nacc >= MAXDET) break;
                    if (!((sup_run >> el) & 1ull)) {
                        amask |= (1ull << el);
                        sup_run |= __shfl(m, el, 64);
                        ++nacc;
                    }
                }
                if ((amask >> lane) & 1ull) {
                    int slot = nacc0 + (int)__popcll(amask & ((1ull << lane) - 1ull));
                    s_ax1[slot] = x1; s_ay1[slot] = y1;
                    s_ax2[slot] = x2; s_ay2[slot] = y2;
                    s_aar[slot] = ar;
                    s_accPK[slot] = pk;
                }
                if (lane == 0) s_nacc = nacc;
            }
            __syncthreads();
            if (s_nacc >= MAXDET) break;
        }

        cum_prev = cumB; kthr_prev = kthr;
        if (s_nacc >= MAXDET || cum_prev >= total) break;
        __syncthreads();
    }

    // ---- outputs: [scs 32x100][lab 32x100][boxes 32x100x4][goods 32x100], f32 ----
    if (tid < MAXDET) {
        const int* ts = tsizes + b * 2;
        float th = (float)ts[0], tw = (float)ts[1];   // (h, w)
        int d = tid;
        bool good = d < s_nacc;
        float sc = 0.0f, lb = -1.0f, gd = 0.0f;
        float ox1 = 0.f, oy1 = 0.f, ox2 = 0.f, oy2 = 0.f;
        if (good) {
            u64 pk = s_accPK[d];
            u32 key = (u32)(pk >> 32);
            u32 idx = ~((u32)pk);
            u32 qq = idx / CN, cc = idx - qq * CN;
            float L = fkey_inv(key);
            sc = 1.0f / (1.0f + expf(-L));
            lb = (float)cc;
            gd = 1.0f;
            ox1 = s_xy[qq].x * tw;
            oy1 = s_xy[qq].y * th;
            ox2 = s_xy[qq].z * tw;
            oy2 = s_xy[qq].w * th;
        }
        out[b * MAXDET + d] = sc;
        out[BIMG * MAXDET + b * MAXDET + d] = lb;
        float* ob = out + 2 * BIMG * MAXDET + (size_t)(b * MAXDET + d) * 4;
        ob[0] = ox1; ob[1] = oy1; ob[2] = ox2; ob[3] = oy2;
        out[2 * BIMG * MAXDET + BIMG * MAXDET * 4 + b * MAXDET + d] = gd;
    }
}

// ================= Fallback: validated round-4 single kernel =================
#define NTHREADS 1024
__device__ __forceinline__ void scan6(const float4* v, int itbase, int tid, int lane,
                                      uint8_t* s_finq, u64* s_list, u32* s_cnt)
{
    #pragma unroll
    for (int j = 0; j < 6; ++j) {
        int i4 = tid + (itbase + j) * NTHREADS;
        bool inb = i4 < NF4;
        float4 vv = v[j];
        int i0 = i4 * 4;
        bool bad = inb && (!isfinite(vv.x) || !isfinite(vv.y) || !isfinite(vv.z) || !isfinite(vv.w));
        if (__any((int)bad)) {
            if (inb) {
                if (!isfinite(vv.x)) s_finq[(i0 + 0) / CN] = 0;
                if (!isfinite(vv.y)) s_finq[(i0 + 1) / CN] = 0;
                if (!isfinite(vv.z)) s_finq[(i0 + 2) / CN] = 0;
                if (!isfinite(vv.w)) s_finq[(i0 + 3) / CN] = 0;
            }
        }
        float Ls[4] = {vv.x, vv.y, vv.z, vv.w};
        #pragma unroll
        for (int s = 0; s < 4; ++s) {
            bool p = inb && (Ls[s] >= PREF);
            u64 mask = __ballot((int)p);
            if (mask) {
                int leader = __ffsll((long long)mask) - 1;
                u32 base = 0;
                if (lane == leader) base = atomicAdd(s_cnt, (u32)__popcll(mask));
                base = (u32)__shfl((int)base, leader, 64);
                if (p) {
                    u32 pos = base + (u32)__popcll(mask & ((1ull << lane) - 1ull));
                    if (pos < CAP) {
                        u32 i = (u32)(i0 + s);
                        s_list[pos] = ((u64)fkey(Ls[s]) << 32) | (u64)(~i);
                    }
                }
            }
        }
    }
}

__global__ __launch_bounds__(NTHREADS)
void ov_post(const float* __restrict__ logits, const float* __restrict__ boxes,
             const int* __restrict__ tsizes, float* __restrict__ out)
{
    __shared__ float   s_xyxy[QN][4];
    __shared__ uint8_t s_finq[QN];
    __shared__ u64     s_list[CAP];
    __shared__ u32     s_offk;
    __shared__ u32     s_cnt;
    __shared__ u64     s_mat[64];
    __shared__ u64     s_wsup[16];
    __shared__ u64     s_vmask;
    __shared__ float   s_ax1[MAXDET], s_ay1[MAXDET], s_ax2[MAXDET], s_ay2[MAXDET], s_aar[MAXDET];
    __shared__ u32     s_accE[MAXDET];
    __shared__ int     s_nacc;
    __shared__ int     s_done;

    const int b = blockIdx.x;
    const int tid = threadIdx.x;
    const int lane = tid & 63;
    const int wv = tid >> 6;
    const float* lg = logits + (size_t)b * NCAND;
    const float4* lg4 = (const float4*)lg;

    if (tid == 0) { s_offk = 0u; s_cnt = 0u; s_nacc = 0; s_done = 0; }
    __syncthreads();

    if (tid < QN) {
        float4 bx = *(const float4*)(boxes + ((size_t)b * QN + tid) * 4);
        float hw = 0.5f * bx.z, hh = 0.5f * bx.w;
        float x1 = bx.x - hw, y1 = bx.y - hh, x2 = bx.x + hw, y2 = bx.y + hh;
        s_xyxy[tid][0] = x1; s_xyxy[tid][1] = y1;
        s_xyxy[tid][2] = x2; s_xyxy[tid][3] = y2;
        s_finq[tid] = (isfinite(x1) && isfinite(y1) && isfinite(x2) && isfinite(y2)) ? 1 : 0;
        u32 k = fkey(isfinite(x1) ? x1 : 0.0f);
        k = max(k, fkey(isfinite(y1) ? y1 : 0.0f));
        k = max(k, fkey(isfinite(x2) ? x2 : 0.0f));
        k = max(k, fkey(isfinite(y2) ? y2 : 0.0f));
        atomicMax(&s_offk, k);
    }
    __syncthreads();

    {
        float4 vA[6], vB[6];
        #pragma unroll
        for (int j = 0; j < 6; ++j) vA[j] = lg4[tid + j * NTHREADS];
        #pragma unroll
        for (int j = 0; j < 6; ++j) vB[j] = lg4[tid + (6 + j) * NTHREADS];
        scan6(vA, 0, tid, lane, s_finq, s_list, &s_cnt);
        #pragma unroll
        for (int j = 0; j < 6; ++j) {
            int i4 = tid + (12 + j) * NTHREADS;
            vA[j] = lg4[(i4 < NF4) ? i4 : (NF4 - 1)];
        }
        scan6(vB, 6, tid, lane, s_finq, s_list, &s_cnt);
        scan6(vA, 12, tid, lane, s_finq, s_list, &s_cnt);
    }
    __syncthreads();

    u32 n = s_cnt; if (n > CAP) n = CAP;
    for (int t = tid; t < CAP; t += NTHREADS) {
        if (t < (int)n) {
            u32 idx = ~((u32)s_list[t]);
            if (!s_finq[idx / CN]) s_list[t] = 0ull;
        } else {
            s_list[t] = 0ull;
        }
    }
    __syncthreads();

    {
        u64 v0 = s_list[tid], v1 = s_list[tid + 1024];
        for (u32 k = 2; k <= 64; k <<= 1)
            for (u32 j = k >> 1; j > 0; j >>= 1) {
                { u64 p = __shfl_xor(v0, (int)j, 64); u32 e = (u32)tid;
                  bool tm = (((e & k) == 0) != ((e & j) != 0)); v0 = (tm == (p > v0)) ? p : v0; }
                { u64 p = __shfl_xor(v1, (int)j, 64); u32 e = (u32)tid + 1024u;
                  bool tm = (((e & k) == 0) != ((e & j) != 0)); v1 = (tm == (p > v1)) ? p : v1; }
            }
        s_list[tid] = v0; s_list[tid + 1024] = v1;
        __syncthreads();
        for (u32 k = 128; k <= 2048; k <<= 1) {
            for (u32 j = k >> 1; j >= 64; j >>= 1) {
                for (u32 t = (u32)tid; t < CAP; t += NTHREADS) {
                    u32 ixj = t ^ j;
                    if (ixj > t) {
                        u64 a = s_list[t], c = s_list[ixj];
                        bool sw = ((t & k) == 0) ? (a < c) : (a > c);
                        if (sw) { s_list[t] = c; s_list[ixj] = a; }
                    }
                }
                __syncthreads();
            }
            v0 = s_list[tid]; v1 = s_list[tid + 1024];
            for (u32 j = 32; j > 0; j >>= 1) {
                { u64 p = __shfl_xor(v0, (int)j, 64); u32 e = (u32)tid;
                  bool tm = (((e & k) == 0) != ((e & j) != 0)); v0 = (tm == (p > v0)) ? p : v0; }
                { u64 p = __shfl_xor(v1, (int)j, 64); u32 e = (u32)tid + 1024u;
                  bool tm = (((e & k) == 0) != ((e & j) != 0)); v1 = (tm == (p > v1)) ? p : v1; }
            }
            s_list[tid] = v0; s_list[tid + 1024] = v1;
            __syncthreads();
        }
    }

    const float off = fkey_inv(s_offk) + 1.0f;
    for (u32 e0 = 0; e0 < n; e0 += 64) {
        u32 e = e0 + (u32)lane;
        u64 pk = (e < n) ? s_list[e] : 0ull;
        bool valid = (pk != 0ull);
        float x1 = 0.f, y1 = 0.f, x2 = 0.f, y2 = 0.f, ar = 0.f;
        if (valid) {
            u32 idx = ~((u32)pk);
            u32 qq = idx / CN, cc = idx - qq * CN;
            float ofc = (float)cc * off;
            x1 = s_xyxy[qq][0] + ofc; y1 = s_xyxy[qq][1] + ofc;
            x2 = s_xyxy[qq][2] + ofc; y2 = s_xyxy[qq][3] + ofc;
            ar = fmaxf(x2 - x1, 0.0f) * fmaxf(y2 - y1, 0.0f);
        }
        #pragma unroll
        for (int rr = 0; rr < 4; ++rr) {
            int r = (wv << 2) | rr;
            float rx1 = __shfl(x1, r, 64), ry1 = __shfl(y1, r, 64);
            float rx2 = __shfl(x2, r, 64), ry2 = __shfl(y2, r, 64);
            float rar = __shfl(ar, r, 64);
            float ltx = fmaxf(rx1, x1), lty = fmaxf(ry1, y1);
            float rbx = fminf(rx2, x2), rby = fminf(ry2, y2);
            float inter = fmaxf(rbx - ltx, 0.0f) * fmaxf(rby - lty, 0.0f);
            float uni = rar + ar - inter;
            bool s = valid && ((inter / fmaxf(uni, 1e-9f)) > 0.5f);
            u64 rm = __ballot((int)s);
            if (lane == 0) s_mat[r] = rm;
        }
        int nacc0 = s_nacc;
        bool sup = false;
        for (int a = wv; a < nacc0; a += 16) {
            float ltx = fmaxf(s_ax1[a], x1), lty = fmaxf(s_ay1[a], y1);
            float rbx = fminf(s_ax2[a], x2), rby = fminf(s_ay2[a], y2);
            float inter = fmaxf(rbx - ltx, 0.0f) * fmaxf(rby - lty, 0.0f);
            float uni = s_aar[a] + ar - inter;
            sup = sup || ((inter / fmaxf(uni, 1e-9f)) > 0.5f);
        }
        u64 wm = __ballot((int)(sup && valid));
        if (lane == 0) s_wsup[wv] = wm;
        u64 vmm = __ballot((int)valid);
        if (tid == 0) s_vmask = vmm;
        __syncthreads();

        if (wv == 0) {
            u64 m = s_mat[lane];
            u64 t = (lane < 16) ? s_wsup[lane] : 0ull;
            t |= __shfl_xor(t, 8, 64);
            t |= __shfl_xor(t, 4, 64);
            t |= __shfl_xor(t, 2, 64);
            t |= __shfl_xor(t, 1, 64);
            u64 sup_run = __shfl(t, 0, 64);
            u64 vm = s_vmask;
            int cnt_rem = (int)((n - e0 < 64u) ? (n - e0) : 64u);
            u64 full = (cnt_rem >= 64) ? ~0ull : ((1ull << cnt_rem) - 1ull);
            bool exhausted = ((vm & full) != full) || (e0 + 64 >= n);
            int nacc = nacc0;
            u64 amask = 0ull;
            for (int el = 0; el < cnt_rem; ++el) {
                if (nacc >= MAXDET) break;
                if (!((vm >> el) & 1ull)) break;
                if (!((sup_run >> el) & 1ull)) {
                    amask |= (1ull << el);
                    sup_run |= __shfl(m, el, 64);
                    ++nacc;
                }
            }
            if ((amask >> lane) & 1ull) {
                int slot = nacc0 + (int)__popcll(amask & ((1ull << lane) - 1ull));
                s_ax1[slot] = x1; s_ay1[slot] = y1;
                s_ax2[slot] = x2; s_ay2[slot] = y2;
                s_aar[slot] = ar;
                s_accE[slot] = e;
            }
            if (lane == 0) {
                s_nacc = nacc;
                if (nacc >= MAXDET || exhausted) s_done = 1;
            }
        }
        __syncthreads();
        if (s_done) break;
    }

    if (tid < MAXDET) {
        const int* ts = tsizes + b * 2;
        float th = (float)ts[0], tw = (float)ts[1];
        int d = tid;
        bool good = d < s_nacc;
        float sc = 0.0f, lb = -1.0f, gd = 0.0f;
        float ox1 = 0.f, oy1 = 0.f, ox2 = 0.f, oy2 = 0.f;
        if (good) {
            u64 pk = s_list[s_accE[d]];
            u32 key = (u32)(pk >> 32);
            u32 idx = ~((u32)pk);
            u32 qq = idx / CN, cc = idx - qq * CN;
            float L = fkey_inv(key);
            sc = 1.0f / (1.0f + expf(-L));
            lb = (float)cc;
            gd = 1.0f;
            ox1 = s_xyxy[qq][0] * tw;
            oy1 = s_xyxy[qq][1] * th;
            ox2 = s_xyxy[qq][2] * tw;
            oy2 = s_xyxy[qq][3] * th;
        }
        out[b * MAXDET + d] = sc;
        out[BIMG * MAXDET + b * MAXDET + d] = lb;
        float* ob = out + 2 * BIMG * MAXDET + (size_t)(b * MAXDET + d) * 4;
        ob[0] = ox1; ob[1] = oy1; ob[2] = ox2; ob[3] = oy2;
        out[2 * BIMG * MAXDET + BIMG * MAXDET * 4 + b * MAXDET + d] = gd;
    }
}

extern "C" void kernel_launch(void* const* d_in, const int* in_sizes, int n_in,
                              void* d_out, int out_size, void* d_ws, size_t ws_size,
                              hipStream_t stream) {
    (void)in_sizes; (void)n_in; (void)out_size;
    const float* logits = (const float*)d_in[0];
    const float* boxes  = (const float*)d_in[1];
    const int*   tsizes = (const int*)d_in[2];
    float* out = (float*)d_out;

    if (ws_size >= (size_t)WS_NEEDED) {
        char* ws = (char*)d_ws;
        u32* gcnt  = (u32*)(ws + WS_GCNT);
        u32* badbm = (u32*)(ws + WS_BADBM);
        u64* gseg  = (u64*)(ws + WS_GSEG);
        k_scan<<<BIMG * NSEG, 256, 0, stream>>>(logits, badbm, gcnt, gseg);
        k_main<<<BIMG, 512, 0, stream>>>(boxes, tsizes, badbm, gcnt, gseg, out);
    } else {
        ov_post<<<BIMG, NTHREADS, 0, stream>>>(logits, boxes, tsizes, out);
    }
}

// Round 11
// 34.784 us; speedup vs baseline: 1.6814x; 1.1291x over previous
//
#include <hip/hip_runtime.h>
#include <math.h>
#include <stdint.h>

#define BIMG 32
#define QN 900
#define CN 80
#define NCAND 72000
#define NF4 18000
#define MAXDET 100
#define CAP 2048
#define PREF 2.0f          // prefilter: only L>=2 can ever be examined (validated r3-r10)
#define SEGCAP 280
#define NSEG 8
#define GATHCAP (NSEG * SEGCAP)   // 2240
#define TIERN 128u
#define TOPCAP 192
#define SORTN 256

typedef unsigned long long u64;
typedef uint32_t u32;

// ---- ws layout (written unconditionally every call; no pre-zero) ----
#define WS_GCNT   0                          // u32[256]
#define WS_BADBM  1024                       // u32[256][4]
#define WS_GSEG   5120                       // u64[256][SEGCAP]
#define WS_NEEDED (5120 + 256 * SEGCAP * 8)  // 578,560 B

__device__ __forceinline__ u32 fkey(float f) {
    u32 u = __float_as_uint(f);
    return (u & 0x80000000u) ? ~u : (u | 0x80000000u);
}
__device__ __forceinline__ float fkey_inv(u32 k) {
    u32 u = (k & 0x80000000u) ? (k ^ 0x80000000u) : ~k;
    return __uint_as_float(u);
}
__device__ __forceinline__ float rlanef(float v, int l) {      // uniform-index broadcast
    return __int_as_float(__builtin_amdgcn_readlane(__float_as_int(v), l));
}
__device__ __forceinline__ u64 rlane64(u64 v, int l) {
    u32 lo = (u32)__builtin_amdgcn_readlane((int)(u32)v, l);
    u32 hi = (u32)__builtin_amdgcn_readlane((int)(u32)(v >> 32), l);
    return ((u64)hi << 32) | (u64)lo;
}

// ================= Kernel A: segment scan (256 blocks x 256 thr) =================
__global__ __launch_bounds__(256)
void k_scan(const float* __restrict__ logits, u32* __restrict__ badbm,
            u32* __restrict__ gcnt, u64* __restrict__ gseg)
{
    __shared__ u64 s_seg[SEGCAP];
    __shared__ u32 s_cnt;
    __shared__ u32 s_badbm[4];
    const int tid = threadIdx.x;
    const int img = blockIdx.x >> 3;
    const int seg = blockIdx.x & 7;
    const u32 qbase = (u32)(seg * 9000) / CN;
    if (tid == 0) s_cnt = 0u;
    if (tid < 4) s_badbm[tid] = 0u;
    __syncthreads();

    const float4* lg4 = (const float4*)(logits + (size_t)img * NCAND + (size_t)seg * 9000);
    float4 va[9];
    #pragma unroll
    for (int i = 0; i < 9; ++i) {
        int f4 = tid + i * 256;
        va[i] = lg4[(f4 < 2250) ? f4 : 0];
    }
    int kc = 0;
    #pragma unroll
    for (int i = 0; i < 9; ++i) {
        int f4 = tid + i * 256;
        bool inb = f4 < 2250;
        float4 vv = va[i];
        int ebase = seg * 9000 + f4 * 4;
        bool bad = inb && (!isfinite(vv.x) || !isfinite(vv.y) || !isfinite(vv.z) || !isfinite(vv.w));
        if (__any((int)bad)) {
            if (bad) {
                float c4[4] = {vv.x, vv.y, vv.z, vv.w};
                #pragma unroll
                for (int s2 = 0; s2 < 4; ++s2) {
                    if (!isfinite(c4[s2])) {
                        u32 q = (u32)(ebase + s2) / CN;
                        u32 lq = q - qbase;
                        atomicOr(&s_badbm[lq >> 5], 1u << (lq & 31));
                    }
                }
            }
        }
        if (inb) kc += (vv.x >= PREF) + (vv.y >= PREF) + (vv.z >= PREF) + (vv.w >= PREF);
    }
    u32 w = kc ? atomicAdd(&s_cnt, (u32)kc) : 0u;
    #pragma unroll
    for (int i = 0; i < 9; ++i) {
        int f4 = tid + i * 256;
        bool inb = f4 < 2250;
        float4 vv = va[i];
        int ebase = seg * 9000 + f4 * 4;
        float Ls[4] = {vv.x, vv.y, vv.z, vv.w};
        #pragma unroll
        for (int s2 = 0; s2 < 4; ++s2) {
            if (inb && Ls[s2] >= PREF) {
                if (w < SEGCAP) {
                    u32 i_img = (u32)(ebase + s2);
                    s_seg[w] = ((u64)fkey(Ls[s2]) << 32) | (u64)(~i_img);
                }
                ++w;
            }
        }
    }
    __syncthreads();
    u32 c = s_cnt; if (c > SEGCAP) c = SEGCAP;
    if (tid == 0) gcnt[img * NSEG + seg] = c;
    if (tid < 4) badbm[(img * NSEG + seg) * 4 + tid] = s_badbm[tid];
    for (u32 k = (u32)tid; k < c; k += 256u)
        gseg[(size_t)(img * NSEG + seg) * SEGCAP + k] = s_seg[k];
}

// ====== Kernel B: gather(prefetched) + tiered select + wave-sort + NMS (512 thr) ======
#define CEd(a, b, d) { if ((d) ? ((a) < (b)) : ((a) > (b))) { u64 t_ = (a); (a) = (b); (b) = t_; } }
#define SHFLS(kk) { \
    bool dblk = ((t4 & (kk)) == 0u); \
    for (u32 j = (kk) >> 1; j >= 4u; j >>= 1u) { \
        bool tm = dblk != ((t4 & j) != 0u); \
        int ls = (int)(j >> 2); \
        u64 p; \
        p = __shfl_xor(v0, ls, 64); v0 = (tm == (p > v0)) ? p : v0; \
        p = __shfl_xor(v1, ls, 64); v1 = (tm == (p > v1)) ? p : v1; \
        p = __shfl_xor(v2, ls, 64); v2 = (tm == (p > v2)) ? p : v2; \
        p = __shfl_xor(v3, ls, 64); v3 = (tm == (p > v3)) ? p : v3; \
    } \
    CEd(v0, v2, dblk); CEd(v1, v3, dblk); \
    CEd(v0, v1, dblk); CEd(v2, v3, dblk); }

__global__ __launch_bounds__(512)
void k_main(const float* __restrict__ boxes, const int* __restrict__ tsizes,
            const u32* __restrict__ badbm, const u32* __restrict__ gcnt,
            const u64* __restrict__ gseg, float* __restrict__ out)
{
    __shared__ u64     s_ent[GATHCAP];    // 17.9 KB
    __shared__ float4  s_xy[QN];          // 14.4 KB
    __shared__ u64     s_list[SORTN];     // 2 KB
    __shared__ u32     s_hist[512];       // histogram -> suffix
    __shared__ u32     s_inv[32];
    __shared__ u32     s_segc[NSEG];
    __shared__ u32     s_wtot[8];
    __shared__ u32     s_offk, s_cnt, s_tc, s_kthr, s_cumB;
    __shared__ u64     s_mat[64];
    __shared__ u64     s_wsup[8];
    __shared__ float   s_ax1[MAXDET], s_ay1[MAXDET], s_ax2[MAXDET], s_ay2[MAXDET], s_aar[MAXDET];
    __shared__ u64     s_accPK[MAXDET];
    __shared__ int     s_nacc;

    const int b = blockIdx.x;
    const int tid = threadIdx.x;
    const int lane = tid & 63;
    const int wv = tid >> 6;

    // ---- entry prefetch: fixed addresses, all latency hidden under box phase ----
    u64 ge[5];
    {
        const u64* gp = gseg + (size_t)b * GATHCAP;
        #pragma unroll
        for (int i = 0; i < 5; ++i) {
            u32 p = (u32)tid + (u32)i * 512u;
            ge[i] = gp[(p < (u32)GATHCAP) ? p : (u32)(GATHCAP - 1)];
        }
    }
    float4 bxa[2];
    #pragma unroll
    for (int i = 0; i < 2; ++i) {
        int q = tid + i * 512;
        bxa[i] = *(const float4*)(boxes + ((size_t)b * QN + ((q < QN) ? q : (QN - 1))) * 4);
    }
    const u32 bbv = badbm[(b * NSEG + wv) * 4 + (lane & 3)];   // used when lane<4
    const u32 gcv = gcnt[b * NSEG + (tid & 7)];                // used when tid<8

    if (tid == 0) { s_offk = 0u; s_cnt = 0u; s_nacc = 0; }
    if (tid < 32) s_inv[tid] = 0u;
    if (tid < NSEG) { s_segc[tid] = (gcv < (u32)SEGCAP) ? gcv : (u32)SEGCAP; }
    s_hist[tid] = 0u;
    __syncthreads();

    // ---- per-segment bad bitmaps -> image bitmap ----
    if (lane < 4) {
        u32 val = bbv;
        if (val) {
            u32 qb = (u32)(wv * 9000) / CN;
            u32 qb5 = qb & 31u, bw = (qb >> 5) + (u32)(lane & 3);
            atomicOr(&s_inv[bw], val << qb5);
            if (qb5) atomicOr(&s_inv[bw + 1], val >> (32u - qb5));
        }
    }
    // ---- boxes -> xyxy, finiteness, off-max ----
    u32 mk = 0u;
    #pragma unroll
    for (int i = 0; i < 2; ++i) {
        int q = tid + i * 512;
        if (q < QN) {
            float4 bx = bxa[i];
            float hw = 0.5f * bx.z, hh = 0.5f * bx.w;
            float x1 = bx.x - hw, y1 = bx.y - hh, x2 = bx.x + hw, y2 = bx.y + hh;
            s_xy[q] = make_float4(x1, y1, x2, y2);
            bool bf = isfinite(x1) && isfinite(y1) && isfinite(x2) && isfinite(y2);
            if (!bf) atomicOr(&s_inv[q >> 5], 1u << (q & 31));
            u32 k = fkey(isfinite(x1) ? x1 : 0.0f);
            k = max(k, fkey(isfinite(y1) ? y1 : 0.0f));
            k = max(k, fkey(isfinite(x2) ? x2 : 0.0f));
            k = max(k, fkey(isfinite(y2) ? y2 : 0.0f));
            mk = max(mk, k);
        }
    }
    #pragma unroll
    for (int d = 32; d > 0; d >>= 1) mk = max(mk, (u32)__shfl_xor((int)mk, d, 64));
    if (lane == 0) atomicMax(&s_offk, mk);
    __syncthreads();

    // ---- filter prefetched slots + two-pass compaction + histogram ----
    {
        bool gk[5]; int kc = 0;
        #pragma unroll
        for (int i = 0; i < 5; ++i) {
            gk[i] = false;
            u32 p = (u32)tid + (u32)i * 512u;
            if (p < (u32)GATHCAP) {
                u32 seg = p / (u32)SEGCAP;
                u32 k = p - seg * (u32)SEGCAP;
                if (k < s_segc[seg]) {
                    u32 q = (~((u32)ge[i])) / CN;
                    if (((s_inv[q >> 5] >> (q & 31)) & 1u) == 0u) { gk[i] = true; ++kc; }
                }
            }
        }
        u32 w = kc ? atomicAdd(&s_cnt, (u32)kc) : 0u;
        #pragma unroll
        for (int i = 0; i < 5; ++i) {
            if (gk[i]) {
                s_ent[w++] = ge[i];
                u32 bin = ((u32)(ge[i] >> 32) - 0xC0000000u) >> 15;
                if (bin > 511u) bin = 511u;
                atomicAdd(&s_hist[bin], 1u);
            }
        }
    }
    __syncthreads();

    // ---- suffix-scan 512 bins (wave shfl + cross-wave combine) ----
    {
        u32 h = s_hist[tid];
        #pragma unroll
        for (int d = 1; d < 64; d <<= 1) {
            u32 o = (u32)__shfl((int)h, (lane + d) & 63, 64);
            h += (lane + d < 64) ? o : 0u;
        }
        if (lane == 0) s_wtot[wv] = h;
        __syncthreads();
        u32 after = 0u;
        for (int w2 = wv + 1; w2 < 8; ++w2) after += s_wtot[w2];
        s_hist[tid] = h + after;
        __syncthreads();
    }
    const u32 total = s_cnt;
    const float off = fkey_inv(s_offk) + 1.0f;

    // ---- tier loop: select next-128-with-ties, sort 256 in wave 0, NMS ----
    u32 cum_prev = 0u, kthr_prev = 0xFFFFFFFFu;
    while (true) {
        if (tid == 0) { s_kthr = 0xC0000000u; s_cumB = total; s_tc = 0u; }
        __syncthreads();
        u32 T = cum_prev + TIERN;
        if (s_hist[tid] >= T && (tid == 511 || s_hist[tid + 1] < T)) {
            s_kthr = 0xC0000000u + ((u32)tid << 15); s_cumB = s_hist[tid];
        }
        __syncthreads();
        if (s_cumB - cum_prev > (u32)TOPCAP) {       // tie overflow: take single next bin
            if (tid == 0) { s_kthr = 0xC0000000u; s_cumB = total; }
            __syncthreads();
            u32 T2 = cum_prev + 1u;
            if (s_hist[tid] >= T2 && (tid == 511 || s_hist[tid + 1] < T2)) {
                s_kthr = 0xC0000000u + ((u32)tid << 15); s_cumB = s_hist[tid];
            }
            __syncthreads();
        }
        const u32 kthr = s_kthr, cumB = s_cumB;

        // compact tier entries (two-pass) + zero sort buffer
        if (tid < SORTN) s_list[tid] = 0ull;
        u64 te[5]; bool tk[5]; int tkc = 0;
        #pragma unroll
        for (int i = 0; i < 5; ++i) {
            tk[i] = false;
            u32 p = (u32)tid + (u32)i * 512u;
            if (p < total) {
                u64 e = s_ent[p];
                u32 key = (u32)(e >> 32);
                if (key >= kthr && key < kthr_prev) { tk[i] = true; te[i] = e; ++tkc; }
            }
        }
        u32 base = tkc ? atomicAdd(&s_tc, (u32)tkc) : 0u;
        __syncthreads();                              // zeros + counts done
        {
            u32 w = base;
            #pragma unroll
            for (int i = 0; i < 5; ++i) {
                if (tk[i]) { if (w < (u32)SORTN) s_list[w] = te[i]; ++w; }
            }
        }
        __syncthreads();
        u32 tc = s_tc; if (tc > (u32)SORTN) tc = (u32)SORTN;

        // ---- bitonic sort descending: 256 elems, wave 0 only, in-register ----
        if (wv == 0) {
            u32 t4 = (u32)lane << 2;
            u64 v0 = s_list[t4], v1 = s_list[t4 + 1], v2 = s_list[t4 + 2], v3 = s_list[t4 + 3];
            CEd(v0, v1, true); CEd(v2, v3, false);                                // k=2
            { bool d = ((t4 & 4u) == 0u);
              CEd(v0, v2, d); CEd(v1, v3, d); CEd(v0, v1, d); CEd(v2, v3, d); }   // k=4
            SHFLS(8u) SHFLS(16u) SHFLS(32u) SHFLS(64u) SHFLS(128u) SHFLS(256u)
            s_list[t4] = v0; s_list[t4 + 1] = v1; s_list[t4 + 2] = v2; s_list[t4 + 3] = v3;
        }
        __syncthreads();

        // ---- chunked-mask greedy NMS (exact; 8 waves; carried accepted set) ----
        for (u32 e0 = 0; e0 < tc; e0 += 64) {
            u32 e = e0 + (u32)lane;
            bool valid = e < tc;
            u64 pk = valid ? s_list[e] : 0ull;
            float x1 = 0.f, y1 = 0.f, x2 = 0.f, y2 = 0.f, ar = 0.f;
            if (valid) {
                u32 idx = ~((u32)pk);
                u32 qq = idx / CN, cc = idx - qq * CN;
                float ofc = (float)cc * off;
                float4 xy = s_xy[qq];
                x1 = xy.x + ofc; y1 = xy.y + ofc; x2 = xy.z + ofc; y2 = xy.w + ofc;
                ar = fmaxf(x2 - x1, 0.0f) * fmaxf(y2 - y1, 0.0f);
            }
            #pragma unroll
            for (int rr = 0; rr < 8; ++rr) {
                int r = (wv << 3) | rr;                       // wave-uniform -> readlane
                float rx1 = rlanef(x1, r), ry1 = rlanef(y1, r);
                float rx2 = rlanef(x2, r), ry2 = rlanef(y2, r);
                float rar = rlanef(ar, r);
                float ltx = fmaxf(rx1, x1), lty = fmaxf(ry1, y1);
                float rbx = fminf(rx2, x2), rby = fminf(ry2, y2);
                float inter = fmaxf(rbx - ltx, 0.0f) * fmaxf(rby - lty, 0.0f);
                float uni = rar + ar - inter;         // area(sel)+area(cand)-inter (ref order)
                bool sp = valid && ((inter / fmaxf(uni, 1e-9f)) > 0.5f);
                u64 rm = __ballot((int)sp);
                if (lane == 0) s_mat[r] = rm;
            }
            int nacc0 = s_nacc;
            bool sup = false;
            for (int a = wv; a < nacc0; a += 8) {
                float ltx = fmaxf(s_ax1[a], x1), lty = fmaxf(s_ay1[a], y1);
                float rbx = fminf(s_ax2[a], x2), rby = fminf(s_ay2[a], y2);
                float inter = fmaxf(rbx - ltx, 0.0f) * fmaxf(rby - lty, 0.0f);
                float uni = s_aar[a] + ar - inter;
                sup = sup || ((inter / fmaxf(uni, 1e-9f)) > 0.5f);
            }
            u64 wm = __ballot((int)(sup && valid));
            if (lane == 0) s_wsup[wv] = wm;
            __syncthreads();

            if (wv == 0) {
                u64 m = s_mat[lane];
                u64 t = (lane < 8) ? s_wsup[lane] : 0ull;
                t |= __shfl_xor(t, 4, 64);
                t |= __shfl_xor(t, 2, 64);
                t |= __shfl_xor(t, 1, 64);
                u64 sup_run = rlane64(t, 0);
                int cnt_rem = (int)((tc - e0 < 64u) ? (tc - e0) : 64u);
                int nacc = nacc0;
                u64 amask = 0ull;
                for (int el = 0; el < cnt_rem; ++el) {
                    if (nacc >= MAXDET) break;
                    if (!((sup_run >> el) & 1ull)) {
                        amask |= (1ull << el);
                        sup_run |= rlane64(m, el);            // uniform el -> readlane
                        ++nacc;
                    }
                }
                if ((amask >> lane) & 1ull) {
                    int slot = nacc0 + (int)__popcll(amask & ((1ull << lane) - 1ull));
                    s_ax1[slot] = x1; s_ay1[slot] = y1;
                    s_ax2[slot] = x2; s_ay2[slot] = y2;
                    s_aar[slot] = ar;
                    s_accPK[slot] = pk;
                }
                if (lane == 0) s_nacc = nacc;
            }
            __syncthreads();
            if (s_nacc >= MAXDET) break;
        }

        cum_prev = cumB; kthr_prev = kthr;
        if (s_nacc >= MAXDET || cum_prev >= total) break;
        __syncthreads();
    }

    // ---- outputs: [scs 32x100][lab 32x100][boxes 32x100x4][goods 32x100], f32 ----
    if (tid < MAXDET) {
        const int* ts = tsizes + b * 2;
        float th = (float)ts[0], tw = (float)ts[1];   // (h, w)
        int d = tid;
        bool good = d < s_nacc;
        float sc = 0.0f, lb = -1.0f, gd = 0.0f;
        float ox1 = 0.f, oy1 = 0.f, ox2 = 0.f, oy2 = 0.f;
        if (good) {
            u64 pk = s_accPK[d];
            u32 key = (u32)(pk >> 32);
            u32 idx = ~((u32)pk);
            u32 qq = idx / CN, cc = idx - qq * CN;
            float L = fkey_inv(key);
            sc = 1.0f / (1.0f + expf(-L));
            lb = (float)cc;
            gd = 1.0f;
            ox1 = s_xy[qq].x * tw;
            oy1 = s_xy[qq].y * th;
            ox2 = s_xy[qq].z * tw;
            oy2 = s_xy[qq].w * th;
        }
        out[b * MAXDET + d] = sc;
        out[BIMG * MAXDET + b * MAXDET + d] = lb;
        float* ob = out + 2 * BIMG * MAXDET + (size_t)(b * MAXDET + d) * 4;
        ob[0] = ox1; ob[1] = oy1; ob[2] = ox2; ob[3] = oy2;
        out[2 * BIMG * MAXDET + BIMG * MAXDET * 4 + b * MAXDET + d] = gd;
    }
}

// ================= Fallback: validated round-4 single kernel =================
#define NTHREADS 1024
__device__ __forceinline__ void scan6(const float4* v, int itbase, int tid, int lane,
                                      uint8_t* s_finq, u64* s_list, u32* s_cnt)
{
    #pragma unroll
    for (int j = 0; j < 6; ++j) {
        int i4 = tid + (itbase + j) * NTHREADS;
        bool inb = i4 < NF4;
        float4 vv = v[j];
        int i0 = i4 * 4;
        bool bad = inb && (!isfinite(vv.x) || !isfinite(vv.y) || !isfinite(vv.z) || !isfinite(vv.w));
        if (__any((int)bad)) {
            if (inb) {
                if (!isfinite(vv.x)) s_finq[(i0 + 0) / CN] = 0;
                if (!isfinite(vv.y)) s_finq[(i0 + 1) / CN] = 0;
                if (!isfinite(vv.z)) s_finq[(i0 + 2) / CN] = 0;
                if (!isfinite(vv.w)) s_finq[(i0 + 3) / CN] = 0;
            }
        }
        float Ls[4] = {vv.x, vv.y, vv.z, vv.w};
        #pragma unroll
        for (int s = 0; s < 4; ++s) {
            bool p = inb && (Ls[s] >= PREF);
            u64 mask = __ballot((int)p);
            if (mask) {
                int leader = __ffsll((long long)mask) - 1;
                u32 base = 0;
                if (lane == leader) base = atomicAdd(s_cnt, (u32)__popcll(mask));
                base = (u32)__shfl((int)base, leader, 64);
                if (p) {
                    u32 pos = base + (u32)__popcll(mask & ((1ull << lane) - 1ull));
                    if (pos < CAP) {
                        u32 i = (u32)(i0 + s);
                        s_list[pos] = ((u64)fkey(Ls[s]) << 32) | (u64)(~i);
                    }
                }
            }
        }
    }
}

__global__ __launch_bounds__(NTHREADS)
void ov_post(const float* __restrict__ logits, const float* __restrict__ boxes,
             const int* __restrict__ tsizes, float* __restrict__ out)
{
    __shared__ float   s_xyxy[QN][4];
    __shared__ uint8_t s_finq[QN];
    __shared__ u64     s_list[CAP];
    __shared__ u32     s_offk;
    __shared__ u32     s_cnt;
    __shared__ u64     s_mat[64];
    __shared__ u64     s_wsup[16];
    __shared__ u64     s_vmask;
    __shared__ float   s_ax1[MAXDET], s_ay1[MAXDET], s_ax2[MAXDET], s_ay2[MAXDET], s_aar[MAXDET];
    __shared__ u32     s_accE[MAXDET];
    __shared__ int     s_nacc;
    __shared__ int     s_done;

    const int b = blockIdx.x;
    const int tid = threadIdx.x;
    const int lane = tid & 63;
    const int wv = tid >> 6;
    const float* lg = logits + (size_t)b * NCAND;
    const float4* lg4 = (const float4*)lg;

    if (tid == 0) { s_offk = 0u; s_cnt = 0u; s_nacc = 0; s_done = 0; }
    __syncthreads();

    if (tid < QN) {
        float4 bx = *(const float4*)(boxes + ((size_t)b * QN + tid) * 4);
        float hw = 0.5f * bx.z, hh = 0.5f * bx.w;
        float x1 = bx.x - hw, y1 = bx.y - hh, x2 = bx.x + hw, y2 = bx.y + hh;
        s_xyxy[tid][0] = x1; s_xyxy[tid][1] = y1;
        s_xyxy[tid][2] = x2; s_xyxy[tid][3] = y2;
        s_finq[tid] = (isfinite(x1) && isfinite(y1) && isfinite(x2) && isfinite(y2)) ? 1 : 0;
        u32 k = fkey(isfinite(x1) ? x1 : 0.0f);
        k = max(k, fkey(isfinite(y1) ? y1 : 0.0f));
        k = max(k, fkey(isfinite(x2) ? x2 : 0.0f));
        k = max(k, fkey(isfinite(y2) ? y2 : 0.0f));
        atomicMax(&s_offk, k);
    }
    __syncthreads();

    {
        float4 vA[6], vB[6];
        #pragma unroll
        for (int j = 0; j < 6; ++j) vA[j] = lg4[tid + j * NTHREADS];
        #pragma unroll
        for (int j = 0; j < 6; ++j) vB[j] = lg4[tid + (6 + j) * NTHREADS];
        scan6(vA, 0, tid, lane, s_finq, s_list, &s_cnt);
        #pragma unroll
        for (int j = 0; j < 6; ++j) {
            int i4 = tid + (12 + j) * NTHREADS;
            vA[j] = lg4[(i4 < NF4) ? i4 : (NF4 - 1)];
        }
        scan6(vB, 6, tid, lane, s_finq, s_list, &s_cnt);
        scan6(vA, 12, tid, lane, s_finq, s_list, &s_cnt);
    }
    __syncthreads();

    u32 n = s_cnt; if (n > CAP) n = CAP;
    for (int t = tid; t < CAP; t += NTHREADS) {
        if (t < (int)n) {
            u32 idx = ~((u32)s_list[t]);
            if (!s_finq[idx / CN]) s_list[t] = 0ull;
        } else {
            s_list[t] = 0ull;
        }
    }
    __syncthreads();

    {
        u64 v0 = s_list[tid], v1 = s_list[tid + 1024];
        for (u32 k = 2; k <= 64; k <<= 1)
            for (u32 j = k >> 1; j > 0; j >>= 1) {
                { u64 p = __shfl_xor(v0, (int)j, 64); u32 e = (u32)tid;
                  bool tm = (((e & k) == 0) != ((e & j) != 0)); v0 = (tm == (p > v0)) ? p : v0; }
                { u64 p = __shfl_xor(v1, (int)j, 64); u32 e = (u32)tid + 1024u;
                  bool tm = (((e & k) == 0) != ((e & j) != 0)); v1 = (tm == (p > v1)) ? p : v1; }
            }
        s_list[tid] = v0; s_list[tid + 1024] = v1;
        __syncthreads();
        for (u32 k = 128; k <= 2048; k <<= 1) {
            for (u32 j = k >> 1; j >= 64; j >>= 1) {
                for (u32 t = (u32)tid; t < CAP; t += NTHREADS) {
                    u32 ixj = t ^ j;
                    if (ixj > t) {
                        u64 a = s_list[t], c = s_list[ixj];
                        bool sw = ((t & k) == 0) ? (a < c) : (a > c);
                        if (sw) { s_list[t] = c; s_list[ixj] = a; }
                    }
                }
                __syncthreads();
            }
            v0 = s_list[tid]; v1 = s_list[tid + 1024];
            for (u32 j = 32; j > 0; j >>= 1) {
                { u64 p = __shfl_xor(v0, (int)j, 64); u32 e = (u32)tid;
                  bool tm = (((e & k) == 0) != ((e & j) != 0)); v0 = (tm == (p > v0)) ? p : v0; }
                { u64 p = __shfl_xor(v1, (int)j, 64); u32 e = (u32)tid + 1024u;
                  bool tm = (((e & k) == 0) != ((e & j) != 0)); v1 = (tm == (p > v1)) ? p : v1; }
            }
            s_list[tid] = v0; s_list[tid + 1024] = v1;
            __syncthreads();
        }
    }

    const float off = fkey_inv(s_offk) + 1.0f;
    for (u32 e0 = 0; e0 < n; e0 += 64) {
        u32 e = e0 + (u32)lane;
        u64 pk = (e < n) ? s_list[e] : 0ull;
        bool valid = (pk != 0ull);
        float x1 = 0.f, y1 = 0.f, x2 = 0.f, y2 = 0.f, ar = 0.f;
        if (valid) {
            u32 idx = ~((u32)pk);
            u32 qq = idx / CN, cc = idx - qq * CN;
            float ofc = (float)cc * off;
            x1 = s_xyxy[qq][0] + ofc; y1 = s_xyxy[qq][1] + ofc;
            x2 = s_xyxy[qq][2] + ofc; y2 = s_xyxy[qq][3] + ofc;
            ar = fmaxf(x2 - x1, 0.0f) * fmaxf(y2 - y1, 0.0f);
        }
        #pragma unroll
        for (int rr = 0; rr < 4; ++rr) {
            int r = (wv << 2) | rr;
            float rx1 = __shfl(x1, r, 64), ry1 = __shfl(y1, r, 64);
            float rx2 = __shfl(x2, r, 64), ry2 = __shfl(y2, r, 64);
            float rar = __shfl(ar, r, 64);
            float ltx = fmaxf(rx1, x1), lty = fmaxf(ry1, y1);
            float rbx = fminf(rx2, x2), rby = fminf(ry2, y2);
            float inter = fmaxf(rbx - ltx, 0.0f) * fmaxf(rby - lty, 0.0f);
            float uni = rar + ar - inter;
            bool s = valid && ((inter / fmaxf(uni, 1e-9f)) > 0.5f);
            u64 rm = __ballot((int)s);
            if (lane == 0) s_mat[r] = rm;
        }
        int nacc0 = s_nacc;
        bool sup = false;
        for (int a = wv; a < nacc0; a += 16) {
            float ltx = fmaxf(s_ax1[a], x1), lty = fmaxf(s_ay1[a], y1);
            float rbx = fminf(s_ax2[a], x2), rby = fminf(s_ay2[a], y2);
            float inter = fmaxf(rbx - ltx, 0.0f) * fmaxf(rby - lty, 0.0f);
            float uni = s_aar[a] + ar - inter;
            sup = sup || ((inter / fmaxf(uni, 1e-9f)) > 0.5f);
        }
        u64 wm = __ballot((int)(sup && valid));
        if (lane == 0) s_wsup[wv] = wm;
        u64 vmm = __ballot((int)valid);
        if (tid == 0) s_vmask = vmm;
        __syncthreads();

        if (wv == 0) {
            u64 m = s_mat[lane];
            u64 t = (lane < 16) ? s_wsup[lane] : 0ull;
            t |= __shfl_xor(t, 8, 64);
            t |= __shfl_xor(t, 4, 64);
            t |= __shfl_xor(t, 2, 64);
            t |= __shfl_xor(t, 1, 64);
            u64 sup_run = __shfl(t, 0, 64);
            u64 vm = s_vmask;
            int cnt_rem = (int)((n - e0 < 64u) ? (n - e0) : 64u);
            u64 full = (cnt_rem >= 64) ? ~0ull : ((1ull << cnt_rem) - 1ull);
            bool exhausted = ((vm & full) != full) || (e0 + 64 >= n);
            int nacc = nacc0;
            u64 amask = 0ull;
            for (int el = 0; el < cnt_rem; ++el) {
                if (nacc >= MAXDET) break;
                if (!((vm >> el) & 1ull)) break;
                if (!((sup_run >> el) & 1ull)) {
                    amask |= (1ull << el);
                    sup_run |= __shfl(m, el, 64);
                    ++nacc;
                }
            }
            if ((amask >> lane) & 1ull) {
                int slot = nacc0 + (int)__popcll(amask & ((1ull << lane) - 1ull));
                s_ax1[slot] = x1; s_ay1[slot] = y1;
                s_ax2[slot] = x2; s_ay2[slot] = y2;
                s_aar[slot] = ar;
                s_accE[slot] = e;
            }
            if (lane == 0) {
                s_nacc = nacc;
                if (nacc >= MAXDET || exhausted) s_done = 1;
            }
        }
        __syncthreads();
        if (s_done) break;
    }

    if (tid < MAXDET) {
        const int* ts = tsizes + b * 2;
        float th = (float)ts[0], tw = (float)ts[1];
        int d = tid;
        bool good = d < s_nacc;
        float sc = 0.0f, lb = -1.0f, gd = 0.0f;
        float ox1 = 0.f, oy1 = 0.f, ox2 = 0.f, oy2 = 0.f;
        if (good) {
            u64 pk = s_list[s_accE[d]];
            u32 key = (u32)(pk >> 32);
            u32 idx = ~((u32)pk);
            u32 qq = idx / CN, cc = idx - qq * CN;
            float L = fkey_inv(key);
            sc = 1.0f / (1.0f + expf(-L));
            lb = (float)cc;
            gd = 1.0f;
            ox1 = s_xyxy[qq][0] * tw;
            oy1 = s_xyxy[qq][1] * th;
            ox2 = s_xyxy[qq][2] * tw;
            oy2 = s_xyxy[qq][3] * th;
        }
        out[b * MAXDET + d] = sc;
        out[BIMG * MAXDET + b * MAXDET + d] = lb;
        float* ob = out + 2 * BIMG * MAXDET + (size_t)(b * MAXDET + d) * 4;
        ob[0] = ox1; ob[1] = oy1; ob[2] = ox2; ob[3] = oy2;
        out[2 * BIMG * MAXDET + BIMG * MAXDET * 4 + b * MAXDET + d] = gd;
    }
}

extern "C" void kernel_launch(void* const* d_in, const int* in_sizes, int n_in,
                              void* d_out, int out_size, void* d_ws, size_t ws_size,
                              hipStream_t stream) {
    (void)in_sizes; (void)n_in; (void)out_size;
    const float* logits = (const float*)d_in[0];
    const float* boxes  = (const float*)d_in[1];
    const int*   tsizes = (const int*)d_in[2];
    float* out = (float*)d_out;

    if (ws_size >= (size_t)WS_NEEDED) {
        char* ws = (char*)d_ws;
        u32* gcnt  = (u32*)(ws + WS_GCNT);
        u32* badbm = (u32*)(ws + WS_BADBM);
        u64* gseg  = (u64*)(ws + WS_GSEG);
        k_scan<<<BIMG * NSEG, 256, 0, stream>>>(logits, badbm, gcnt, gseg);
        k_main<<<BIMG, 512, 0, stream>>>(boxes, tsizes, badbm, gcnt, gseg, out);
    } else {
        ov_post<<<BIMG, NTHREADS, 0, stream>>>(logits, boxes, tsizes, out);
    }
}

// Round 12
// 32.623 us; speedup vs baseline: 1.7928x; 1.0663x over previous
//
#include <hip/hip_runtime.h>
#include <math.h>
#include <stdint.h>

#define BIMG 32
#define QN 900
#define CN 80
#define NCAND 72000
#define NF4 18000
#define MAXDET 100
#define CAP 2048
#define PREF 2.0f          // prefilter: only L>=2 can ever be examined (validated r3-r11)
#define SEGCAP 280
#define NSEG 8
#define GATHCAP (NSEG * SEGCAP)   // 2240
#define TIERN 128u
#define TOPCAP 192
#define SORTN 256

typedef unsigned long long u64;
typedef uint32_t u32;

// ---- ws layout (written unconditionally every call; no pre-zero) ----
#define WS_GCNT   0                          // u32[256]
#define WS_BADBM  1024                       // u32[256][4]
#define WS_GSEG   5120                       // u64[256][SEGCAP]
#define WS_NEEDED (5120 + 256 * SEGCAP * 8)  // 578,560 B

__device__ __forceinline__ u32 fkey(float f) {
    u32 u = __float_as_uint(f);
    return (u & 0x80000000u) ? ~u : (u | 0x80000000u);
}
__device__ __forceinline__ float fkey_inv(u32 k) {
    u32 u = (k & 0x80000000u) ? (k ^ 0x80000000u) : ~k;
    return __uint_as_float(u);
}
__device__ __forceinline__ float rlanef(float v, int l) {      // uniform-index broadcast
    return __int_as_float(__builtin_amdgcn_readlane(__float_as_int(v), l));
}
__device__ __forceinline__ u64 rlane64(u64 v, int l) {
    u32 lo = (u32)__builtin_amdgcn_readlane((int)(u32)v, l);
    u32 hi = (u32)__builtin_amdgcn_readlane((int)(u32)(v >> 32), l);
    return ((u64)hi << 32) | (u64)lo;
}

// ================= Kernel A: segment scan (256 blocks x 256 thr) =================
__global__ __launch_bounds__(256)
void k_scan(const float* __restrict__ logits, u32* __restrict__ badbm,
            u32* __restrict__ gcnt, u64* __restrict__ gseg)
{
    __shared__ u64 s_seg[SEGCAP];
    __shared__ u32 s_cnt;
    __shared__ u32 s_badbm[4];
    const int tid = threadIdx.x;
    const int img = blockIdx.x >> 3;
    const int seg = blockIdx.x & 7;
    const u32 qbase = (u32)(seg * 9000) / CN;
    if (tid == 0) s_cnt = 0u;
    if (tid < 4) s_badbm[tid] = 0u;
    __syncthreads();

    const float4* lg4 = (const float4*)(logits + (size_t)img * NCAND + (size_t)seg * 9000);
    float4 va[9];
    #pragma unroll
    for (int i = 0; i < 9; ++i) {
        int f4 = tid + i * 256;
        va[i] = lg4[(f4 < 2250) ? f4 : 0];
    }
    int kc = 0;
    #pragma unroll
    for (int i = 0; i < 9; ++i) {
        int f4 = tid + i * 256;
        bool inb = f4 < 2250;
        float4 vv = va[i];
        int ebase = seg * 9000 + f4 * 4;
        bool bad = inb && (!isfinite(vv.x) || !isfinite(vv.y) || !isfinite(vv.z) || !isfinite(vv.w));
        if (__any((int)bad)) {
            if (bad) {
                float c4[4] = {vv.x, vv.y, vv.z, vv.w};
                #pragma unroll
                for (int s2 = 0; s2 < 4; ++s2) {
                    if (!isfinite(c4[s2])) {
                        u32 q = (u32)(ebase + s2) / CN;
                        u32 lq = q - qbase;
                        atomicOr(&s_badbm[lq >> 5], 1u << (lq & 31));
                    }
                }
            }
        }
        if (inb) kc += (vv.x >= PREF) + (vv.y >= PREF) + (vv.z >= PREF) + (vv.w >= PREF);
    }
    u32 w = kc ? atomicAdd(&s_cnt, (u32)kc) : 0u;
    #pragma unroll
    for (int i = 0; i < 9; ++i) {
        int f4 = tid + i * 256;
        bool inb = f4 < 2250;
        float4 vv = va[i];
        int ebase = seg * 9000 + f4 * 4;
        float Ls[4] = {vv.x, vv.y, vv.z, vv.w};
        #pragma unroll
        for (int s2 = 0; s2 < 4; ++s2) {
            if (inb && Ls[s2] >= PREF) {
                if (w < SEGCAP) {
                    u32 i_img = (u32)(ebase + s2);
                    s_seg[w] = ((u64)fkey(Ls[s2]) << 32) | (u64)(~i_img);
                }
                ++w;
            }
        }
    }
    __syncthreads();
    u32 c = s_cnt; if (c > SEGCAP) c = SEGCAP;
    if (tid == 0) gcnt[img * NSEG + seg] = c;
    if (tid < 4) badbm[(img * NSEG + seg) * 4 + tid] = s_badbm[tid];
    for (u32 k = (u32)tid; k < c; k += 256u)
        gseg[(size_t)(img * NSEG + seg) * SEGCAP + k] = s_seg[k];
}

// ====== Kernel B: register-resident gather + tiered select + wave-sort + NMS ======
#define CEd(a, b, d) { if ((d) ? ((a) < (b)) : ((a) > (b))) { u64 t_ = (a); (a) = (b); (b) = t_; } }
#define SHFLS(kk) { \
    bool dblk = ((t4 & (kk)) == 0u); \
    for (u32 j = (kk) >> 1; j >= 4u; j >>= 1u) { \
        bool tm = dblk != ((t4 & j) != 0u); \
        int ls = (int)(j >> 2); \
        u64 p; \
        p = __shfl_xor(v0, ls, 64); v0 = (tm == (p > v0)) ? p : v0; \
        p = __shfl_xor(v1, ls, 64); v1 = (tm == (p > v1)) ? p : v1; \
        p = __shfl_xor(v2, ls, 64); v2 = (tm == (p > v2)) ? p : v2; \
        p = __shfl_xor(v3, ls, 64); v3 = (tm == (p > v3)) ? p : v3; \
    } \
    CEd(v0, v2, dblk); CEd(v1, v3, dblk); \
    CEd(v0, v1, dblk); CEd(v2, v3, dblk); }

__global__ __launch_bounds__(512)
void k_main(const float* __restrict__ boxes, const int* __restrict__ tsizes,
            const u32* __restrict__ badbm, const u32* __restrict__ gcnt,
            const u64* __restrict__ gseg, float* __restrict__ out)
{
    __shared__ float4  s_xy[QN];          // 14.4 KB
    __shared__ u64     s_list[SORTN];     // 2 KB
    __shared__ u32     s_hist[512];       // histogram -> suffix
    __shared__ u32     s_inv[32];
    __shared__ u32     s_segc[NSEG];
    __shared__ u32     s_wtot[8];
    __shared__ u32     s_offk, s_cnt, s_tc, s_kthr, s_cumB;
    __shared__ u64     s_mat[64];
    __shared__ u64     s_wsup[8];
    __shared__ float   s_ax1[MAXDET], s_ay1[MAXDET], s_ax2[MAXDET], s_ay2[MAXDET], s_aar[MAXDET];
    __shared__ u64     s_accPK[MAXDET];
    __shared__ int     s_nacc;

    const int b = blockIdx.x;
    const int tid = threadIdx.x;
    const int lane = tid & 63;
    const int wv = tid >> 6;

    // ---- entry prefetch: fixed addresses, latency hidden under box phase ----
    u64 ge[5];
    {
        const u64* gp = gseg + (size_t)b * GATHCAP;
        #pragma unroll
        for (int i = 0; i < 5; ++i) {
            u32 p = (u32)tid + (u32)i * 512u;
            ge[i] = gp[(p < (u32)GATHCAP) ? p : (u32)(GATHCAP - 1)];
        }
    }
    float4 bxa[2];
    #pragma unroll
    for (int i = 0; i < 2; ++i) {
        int q = tid + i * 512;
        bxa[i] = *(const float4*)(boxes + ((size_t)b * QN + ((q < QN) ? q : (QN - 1))) * 4);
    }
    const u32 bbv = badbm[(b * NSEG + wv) * 4 + (lane & 3)];   // used when lane<4
    const u32 gcv = gcnt[b * NSEG + (tid & 7)];                // used when tid<8
    const int ts_h = tsizes[b * 2];                            // prefetch output scale
    const int ts_w = tsizes[b * 2 + 1];

    if (tid == 0) { s_offk = 0u; s_cnt = 0u; s_nacc = 0; }
    if (tid < 32) s_inv[tid] = 0u;
    if (tid < NSEG) { s_segc[tid] = (gcv < (u32)SEGCAP) ? gcv : (u32)SEGCAP; }
    s_hist[tid] = 0u;
    __syncthreads();

    // ---- per-segment bad bitmaps -> image bitmap ----
    if (lane < 4) {
        u32 val = bbv;
        if (val) {
            u32 qb = (u32)(wv * 9000) / CN;
            u32 qb5 = qb & 31u, bw = (qb >> 5) + (u32)(lane & 3);
            atomicOr(&s_inv[bw], val << qb5);
            if (qb5) atomicOr(&s_inv[bw + 1], val >> (32u - qb5));
        }
    }
    // ---- boxes -> xyxy, finiteness, off-max ----
    u32 mk = 0u;
    #pragma unroll
    for (int i = 0; i < 2; ++i) {
        int q = tid + i * 512;
        if (q < QN) {
            float4 bx = bxa[i];
            float hw = 0.5f * bx.z, hh = 0.5f * bx.w;
            float x1 = bx.x - hw, y1 = bx.y - hh, x2 = bx.x + hw, y2 = bx.y + hh;
            s_xy[q] = make_float4(x1, y1, x2, y2);
            bool bf = isfinite(x1) && isfinite(y1) && isfinite(x2) && isfinite(y2);
            if (!bf) atomicOr(&s_inv[q >> 5], 1u << (q & 31));
            u32 k = fkey(isfinite(x1) ? x1 : 0.0f);
            k = max(k, fkey(isfinite(y1) ? y1 : 0.0f));
            k = max(k, fkey(isfinite(x2) ? x2 : 0.0f));
            k = max(k, fkey(isfinite(y2) ? y2 : 0.0f));
            mk = max(mk, k);
        }
    }
    #pragma unroll
    for (int d = 32; d > 0; d >>= 1) mk = max(mk, (u32)__shfl_xor((int)mk, d, 64));
    if (lane == 0) atomicMax(&s_offk, mk);
    __syncthreads();

    // ---- filter prefetched slots (registers) + total count + histogram ----
    bool gk[5];
    {
        int kc = 0;
        #pragma unroll
        for (int i = 0; i < 5; ++i) {
            gk[i] = false;
            u32 p = (u32)tid + (u32)i * 512u;
            if (p < (u32)GATHCAP) {
                u32 seg = p / (u32)SEGCAP;
                u32 k = p - seg * (u32)SEGCAP;
                if (k < s_segc[seg]) {
                    u32 q = (~((u32)ge[i])) / CN;
                    if (((s_inv[q >> 5] >> (q & 31)) & 1u) == 0u) { gk[i] = true; ++kc; }
                }
            }
        }
        u32 kcr = (u32)kc;                      // wave reduce, 8 atomics total
        #pragma unroll
        for (int d = 32; d > 0; d >>= 1) kcr += (u32)__shfl_xor((int)kcr, d, 64);
        if (lane == 0) atomicAdd(&s_cnt, kcr);
        #pragma unroll
        for (int i = 0; i < 5; ++i) {
            if (gk[i]) {
                u32 bin = ((u32)(ge[i] >> 32) - 0xC0000000u) >> 15;
                if (bin > 511u) bin = 511u;
                atomicAdd(&s_hist[bin], 1u);
            }
        }
    }
    __syncthreads();

    // ---- suffix-scan 512 bins (wave shfl + cross-wave combine) ----
    {
        u32 h = s_hist[tid];
        #pragma unroll
        for (int d = 1; d < 64; d <<= 1) {
            u32 o = (u32)__shfl((int)h, (lane + d) & 63, 64);
            h += (lane + d < 64) ? o : 0u;
        }
        if (lane == 0) s_wtot[wv] = h;
        __syncthreads();
        u32 after = 0u;
        for (int w2 = wv + 1; w2 < 8; ++w2) after += s_wtot[w2];
        s_hist[tid] = h + after;
        __syncthreads();
    }
    const u32 total = s_cnt;
    const float off = fkey_inv(s_offk) + 1.0f;

    // ---- tier loop: select next-128-with-ties, sort 256 in wave 0, NMS ----
    u32 cum_prev = 0u, kthr_prev = 0xFFFFFFFFu;
    while (true) {
        if (tid == 0) { s_kthr = 0xC0000000u; s_cumB = total; s_tc = 0u; }
        __syncthreads();
        u32 T = cum_prev + TIERN;
        if (s_hist[tid] >= T && (tid == 511 || s_hist[tid + 1] < T)) {
            s_kthr = 0xC0000000u + ((u32)tid << 15); s_cumB = s_hist[tid];
        }
        __syncthreads();
        if (s_cumB - cum_prev > (u32)TOPCAP) {       // tie overflow: take single next bin
            if (tid == 0) { s_kthr = 0xC0000000u; s_cumB = total; }
            __syncthreads();
            u32 T2 = cum_prev + 1u;
            if (s_hist[tid] >= T2 && (tid == 511 || s_hist[tid + 1] < T2)) {
                s_kthr = 0xC0000000u + ((u32)tid << 15); s_cumB = s_hist[tid];
            }
            __syncthreads();
        }
        const u32 kthr = s_kthr, cumB = s_cumB;

        // compact tier entries straight from registers (two-pass) + zero sort buffer
        if (tid < SORTN) s_list[tid] = 0ull;
        bool tk[5]; int tkc = 0;
        #pragma unroll
        for (int i = 0; i < 5; ++i) {
            u32 key = (u32)(ge[i] >> 32);
            tk[i] = gk[i] && key >= kthr && key < kthr_prev;
            tkc += tk[i] ? 1 : 0;
        }
        u32 base = tkc ? atomicAdd(&s_tc, (u32)tkc) : 0u;
        __syncthreads();                              // zeros + counts done
        {
            u32 w = base;
            #pragma unroll
            for (int i = 0; i < 5; ++i) {
                if (tk[i]) { if (w < (u32)SORTN) s_list[w] = ge[i]; ++w; }
            }
        }
        __syncthreads();
        u32 tc = s_tc; if (tc > (u32)SORTN) tc = (u32)SORTN;

        // ---- bitonic sort descending: 256 elems, wave 0 only, in-register ----
        if (wv == 0) {
            u32 t4 = (u32)lane << 2;
            u64 v0 = s_list[t4], v1 = s_list[t4 + 1], v2 = s_list[t4 + 2], v3 = s_list[t4 + 3];
            CEd(v0, v1, true); CEd(v2, v3, false);                                // k=2
            { bool d = ((t4 & 4u) == 0u);
              CEd(v0, v2, d); CEd(v1, v3, d); CEd(v0, v1, d); CEd(v2, v3, d); }   // k=4
            SHFLS(8u) SHFLS(16u) SHFLS(32u) SHFLS(64u) SHFLS(128u) SHFLS(256u)
            s_list[t4] = v0; s_list[t4 + 1] = v1; s_list[t4 + 2] = v2; s_list[t4 + 3] = v3;
        }
        __syncthreads();

        // ---- chunked-mask greedy NMS (exact; 8 waves; carried accepted set) ----
        for (u32 e0 = 0; e0 < tc; e0 += 64) {
            u32 e = e0 + (u32)lane;
            bool valid = e < tc;
            u64 pk = valid ? s_list[e] : 0ull;
            float x1 = 0.f, y1 = 0.f, x2 = 0.f, y2 = 0.f, ar = 0.f;
            if (valid) {
                u32 idx = ~((u32)pk);
                u32 qq = idx / CN, cc = idx - qq * CN;
                float ofc = (float)cc * off;
                float4 xy = s_xy[qq];
                x1 = xy.x + ofc; y1 = xy.y + ofc; x2 = xy.z + ofc; y2 = xy.w + ofc;
                ar = fmaxf(x2 - x1, 0.0f) * fmaxf(y2 - y1, 0.0f);
            }
            #pragma unroll
            for (int rr = 0; rr < 8; ++rr) {
                int r = (wv << 3) | rr;                       // wave-uniform -> readlane
                float rx1 = rlanef(x1, r), ry1 = rlanef(y1, r);
                float rx2 = rlanef(x2, r), ry2 = rlanef(y2, r);
                float rar = rlanef(ar, r);
                float ltx = fmaxf(rx1, x1), lty = fmaxf(ry1, y1);
                float rbx = fminf(rx2, x2), rby = fminf(ry2, y2);
                float inter = fmaxf(rbx - ltx, 0.0f) * fmaxf(rby - lty, 0.0f);
                float uni = rar + ar - inter;         // area(sel)+area(cand)-inter (ref order)
                bool sp = valid && ((inter / fmaxf(uni, 1e-9f)) > 0.5f);
                u64 rm = __ballot((int)sp);
                if (lane == 0) s_mat[r] = rm;
            }
            int nacc0 = s_nacc;
            bool sup = false;
            for (int a = wv; a < nacc0; a += 8) {
                float ltx = fmaxf(s_ax1[a], x1), lty = fmaxf(s_ay1[a], y1);
                float rbx = fminf(s_ax2[a], x2), rby = fminf(s_ay2[a], y2);
                float inter = fmaxf(rbx - ltx, 0.0f) * fmaxf(rby - lty, 0.0f);
                float uni = s_aar[a] + ar - inter;
                sup = sup || ((inter / fmaxf(uni, 1e-9f)) > 0.5f);
            }
            u64 wm = __ballot((int)(sup && valid));
            if (lane == 0) s_wsup[wv] = wm;
            __syncthreads();

            if (wv == 0) {
                u64 m = s_mat[lane];
                u64 t = (lane < 8) ? s_wsup[lane] : 0ull;
                t |= __shfl_xor(t, 4, 64);
                t |= __shfl_xor(t, 2, 64);
                t |= __shfl_xor(t, 1, 64);
                u64 sup_run = rlane64(t, 0);
                int cnt_rem = (int)((tc - e0 < 64u) ? (tc - e0) : 64u);
                int nacc = nacc0;
                u64 amask = 0ull;
                for (int el = 0; el < cnt_rem; ++el) {
                    if (nacc >= MAXDET) break;
                    if (!((sup_run >> el) & 1ull)) {
                        amask |= (1ull << el);
                        sup_run |= rlane64(m, el);            // uniform el -> readlane
                        ++nacc;
                    }
                }
                if ((amask >> lane) & 1ull) {
                    int slot = nacc0 + (int)__popcll(amask & ((1ull << lane) - 1ull));
                    s_ax1[slot] = x1; s_ay1[slot] = y1;
                    s_ax2[slot] = x2; s_ay2[slot] = y2;
                    s_aar[slot] = ar;
                    s_accPK[slot] = pk;
                }
                if (lane == 0) s_nacc = nacc;
            }
            __syncthreads();
            if (s_nacc >= MAXDET) break;
        }

        cum_prev = cumB; kthr_prev = kthr;
        if (s_nacc >= MAXDET || cum_prev >= total) break;
        __syncthreads();
    }

    // ---- outputs: [scs 32x100][lab 32x100][boxes 32x100x4][goods 32x100], f32 ----
    if (tid < MAXDET) {
        float th = (float)ts_h, tw = (float)ts_w;     // prefetched (h, w)
        int d = tid;
        bool good = d < s_nacc;
        float sc = 0.0f, lb = -1.0f, gd = 0.0f;
        float ox1 = 0.f, oy1 = 0.f, ox2 = 0.f, oy2 = 0.f;
        if (good) {
            u64 pk = s_accPK[d];
            u32 key = (u32)(pk >> 32);
            u32 idx = ~((u32)pk);
            u32 qq = idx / CN, cc = idx - qq * CN;
            float L = fkey_inv(key);
            sc = 1.0f / (1.0f + expf(-L));
            lb = (float)cc;
            gd = 1.0f;
            ox1 = s_xy[qq].x * tw;
            oy1 = s_xy[qq].y * th;
            ox2 = s_xy[qq].z * tw;
            oy2 = s_xy[qq].w * th;
        }
        out[b * MAXDET + d] = sc;
        out[BIMG * MAXDET + b * MAXDET + d] = lb;
        float* ob = out + 2 * BIMG * MAXDET + (size_t)(b * MAXDET + d) * 4;
        ob[0] = ox1; ob[1] = oy1; ob[2] = ox2; ob[3] = oy2;
        out[2 * BIMG * MAXDET + BIMG * MAXDET * 4 + b * MAXDET + d] = gd;
    }
}

// ================= Fallback: validated round-4 single kernel =================
#define NTHREADS 1024
__device__ __forceinline__ void scan6(const float4* v, int itbase, int tid, int lane,
                                      uint8_t* s_finq, u64* s_list, u32* s_cnt)
{
    #pragma unroll
    for (int j = 0; j < 6; ++j) {
        int i4 = tid + (itbase + j) * NTHREADS;
        bool inb = i4 < NF4;
        float4 vv = v[j];
        int i0 = i4 * 4;
        bool bad = inb && (!isfinite(vv.x) || !isfinite(vv.y) || !isfinite(vv.z) || !isfinite(vv.w));
        if (__any((int)bad)) {
            if (inb) {
                if (!isfinite(vv.x)) s_finq[(i0 + 0) / CN] = 0;
                if (!isfinite(vv.y)) s_finq[(i0 + 1) / CN] = 0;
                if (!isfinite(vv.z)) s_finq[(i0 + 2) / CN] = 0;
                if (!isfinite(vv.w)) s_finq[(i0 + 3) / CN] = 0;
            }
        }
        float Ls[4] = {vv.x, vv.y, vv.z, vv.w};
        #pragma unroll
        for (int s = 0; s < 4; ++s) {
            bool p = inb && (Ls[s] >= PREF);
            u64 mask = __ballot((int)p);
            if (mask) {
                int leader = __ffsll((long long)mask) - 1;
                u32 base = 0;
                if (lane == leader) base = atomicAdd(s_cnt, (u32)__popcll(mask));
                base = (u32)__shfl((int)base, leader, 64);
                if (p) {
                    u32 pos = base + (u32)__popcll(mask & ((1ull << lane) - 1ull));
                    if (pos < CAP) {
                        u32 i = (u32)(i0 + s);
                        s_list[pos] = ((u64)fkey(Ls[s]) << 32) | (u64)(~i);
                    }
                }
            }
        }
    }
}

__global__ __launch_bounds__(NTHREADS)
void ov_post(const float* __restrict__ logits, const float* __restrict__ boxes,
             const int* __restrict__ tsizes, float* __restrict__ out)
{
    __shared__ float   s_xyxy[QN][4];
    __shared__ uint8_t s_finq[QN];
    __shared__ u64     s_list[CAP];
    __shared__ u32     s_offk;
    __shared__ u32     s_cnt;
    __shared__ u64     s_mat[64];
    __shared__ u64     s_wsup[16];
    __shared__ u64     s_vmask;
    __shared__ float   s_ax1[MAXDET], s_ay1[MAXDET], s_ax2[MAXDET], s_ay2[MAXDET], s_aar[MAXDET];
    __shared__ u32     s_accE[MAXDET];
    __shared__ int     s_nacc;
    __shared__ int     s_done;

    const int b = blockIdx.x;
    const int tid = threadIdx.x;
    const int lane = tid & 63;
    const int wv = tid >> 6;
    const float* lg = logits + (size_t)b * NCAND;
    const float4* lg4 = (const float4*)lg;

    if (tid == 0) { s_offk = 0u; s_cnt = 0u; s_nacc = 0; s_done = 0; }
    __syncthreads();

    if (tid < QN) {
        float4 bx = *(const float4*)(boxes + ((size_t)b * QN + tid) * 4);
        float hw = 0.5f * bx.z, hh = 0.5f * bx.w;
        float x1 = bx.x - hw, y1 = bx.y - hh, x2 = bx.x + hw, y2 = bx.y + hh;
        s_xyxy[tid][0] = x1; s_xyxy[tid][1] = y1;
        s_xyxy[tid][2] = x2; s_xyxy[tid][3] = y2;
        s_finq[tid] = (isfinite(x1) && isfinite(y1) && isfinite(x2) && isfinite(y2)) ? 1 : 0;
        u32 k = fkey(isfinite(x1) ? x1 : 0.0f);
        k = max(k, fkey(isfinite(y1) ? y1 : 0.0f));
        k = max(k, fkey(isfinite(x2) ? x2 : 0.0f));
        k = max(k, fkey(isfinite(y2) ? y2 : 0.0f));
        atomicMax(&s_offk, k);
    }
    __syncthreads();

    {
        float4 vA[6], vB[6];
        #pragma unroll
        for (int j = 0; j < 6; ++j) vA[j] = lg4[tid + j * NTHREADS];
        #pragma unroll
        for (int j = 0; j < 6; ++j) vB[j] = lg4[tid + (6 + j) * NTHREADS];
        scan6(vA, 0, tid, lane, s_finq, s_list, &s_cnt);
        #pragma unroll
        for (int j = 0; j < 6; ++j) {
            int i4 = tid + (12 + j) * NTHREADS;
            vA[j] = lg4[(i4 < NF4) ? i4 : (NF4 - 1)];
        }
        scan6(vB, 6, tid, lane, s_finq, s_list, &s_cnt);
        scan6(vA, 12, tid, lane, s_finq, s_list, &s_cnt);
    }
    __syncthreads();

    u32 n = s_cnt; if (n > CAP) n = CAP;
    for (int t = tid; t < CAP; t += NTHREADS) {
        if (t < (int)n) {
            u32 idx = ~((u32)s_list[t]);
            if (!s_finq[idx / CN]) s_list[t] = 0ull;
        } else {
            s_list[t] = 0ull;
        }
    }
    __syncthreads();

    {
        u64 v0 = s_list[tid], v1 = s_list[tid + 1024];
        for (u32 k = 2; k <= 64; k <<= 1)
            for (u32 j = k >> 1; j > 0; j >>= 1) {
                { u64 p = __shfl_xor(v0, (int)j, 64); u32 e = (u32)tid;
                  bool tm = (((e & k) == 0) != ((e & j) != 0)); v0 = (tm == (p > v0)) ? p : v0; }
                { u64 p = __shfl_xor(v1, (int)j, 64); u32 e = (u32)tid + 1024u;
                  bool tm = (((e & k) == 0) != ((e & j) != 0)); v1 = (tm == (p > v1)) ? p : v1; }
            }
        s_list[tid] = v0; s_list[tid + 1024] = v1;
        __syncthreads();
        for (u32 k = 128; k <= 2048; k <<= 1) {
            for (u32 j = k >> 1; j >= 64; j >>= 1) {
                for (u32 t = (u32)tid; t < CAP; t += NTHREADS) {
                    u32 ixj = t ^ j;
                    if (ixj > t) {
                        u64 a = s_list[t], c = s_list[ixj];
                        bool sw = ((t & k) == 0) ? (a < c) : (a > c);
                        if (sw) { s_list[t] = c; s_list[ixj] = a; }
                    }
                }
                __syncthreads();
            }
            v0 = s_list[tid]; v1 = s_list[tid + 1024];
            for (u32 j = 32; j > 0; j >>= 1) {
                { u64 p = __shfl_xor(v0, (int)j, 64); u32 e = (u32)tid;
                  bool tm = (((e & k) == 0) != ((e & j) != 0)); v0 = (tm == (p > v0)) ? p : v0; }
                { u64 p = __shfl_xor(v1, (int)j, 64); u32 e = (u32)tid + 1024u;
                  bool tm = (((e & k) == 0) != ((e & j) != 0)); v1 = (tm == (p > v1)) ? p : v1; }
            }
            s_list[tid] = v0; s_list[tid + 1024] = v1;
            __syncthreads();
        }
    }

    const float off = fkey_inv(s_offk) + 1.0f;
    for (u32 e0 = 0; e0 < n; e0 += 64) {
        u32 e = e0 + (u32)lane;
        u64 pk = (e < n) ? s_list[e] : 0ull;
        bool valid = (pk != 0ull);
        float x1 = 0.f, y1 = 0.f, x2 = 0.f, y2 = 0.f, ar = 0.f;
        if (valid) {
            u32 idx = ~((u32)pk);
            u32 qq = idx / CN, cc = idx - qq * CN;
            float ofc = (float)cc * off;
            x1 = s_xyxy[qq][0] + ofc; y1 = s_xyxy[qq][1] + ofc;
            x2 = s_xyxy[qq][2] + ofc; y2 = s_xyxy[qq][3] + ofc;
            ar = fmaxf(x2 - x1, 0.0f) * fmaxf(y2 - y1, 0.0f);
        }
        #pragma unroll
        for (int rr = 0; rr < 4; ++rr) {
            int r = (wv << 2) | rr;
            float rx1 = __shfl(x1, r, 64), ry1 = __shfl(y1, r, 64);
            float rx2 = __shfl(x2, r, 64), ry2 = __shfl(y2, r, 64);
            float rar = __shfl(ar, r, 64);
            float ltx = fmaxf(rx1, x1), lty = fmaxf(ry1, y1);
            float rbx = fminf(rx2, x2), rby = fminf(ry2, y2);
            float inter = fmaxf(rbx - ltx, 0.0f) * fmaxf(rby - lty, 0.0f);
            float uni = rar + ar - inter;
            bool s = valid && ((inter / fmaxf(uni, 1e-9f)) > 0.5f);
            u64 rm = __ballot((int)s);
            if (lane == 0) s_mat[r] = rm;
        }
        int nacc0 = s_nacc;
        bool sup = false;
        for (int a = wv; a < nacc0; a += 16) {
            float ltx = fmaxf(s_ax1[a], x1), lty = fmaxf(s_ay1[a], y1);
            float rbx = fminf(s_ax2[a], x2), rby = fminf(s_ay2[a], y2);
            float inter = fmaxf(rbx - ltx, 0.0f) * fmaxf(rby - lty, 0.0f);
            float uni = s_aar[a] + ar - inter;
            sup = sup || ((inter / fmaxf(uni, 1e-9f)) > 0.5f);
        }
        u64 wm = __ballot((int)(sup && valid));
        if (lane == 0) s_wsup[wv] = wm;
        u64 vmm = __ballot((int)valid);
        if (tid == 0) s_vmask = vmm;
        __syncthreads();

        if (wv == 0) {
            u64 m = s_mat[lane];
            u64 t = (lane < 16) ? s_wsup[lane] : 0ull;
            t |= __shfl_xor(t, 8, 64);
            t |= __shfl_xor(t, 4, 64);
            t |= __shfl_xor(t, 2, 64);
            t |= __shfl_xor(t, 1, 64);
            u64 sup_run = __shfl(t, 0, 64);
            u64 vm = s_vmask;
            int cnt_rem = (int)((n - e0 < 64u) ? (n - e0) : 64u);
            u64 full = (cnt_rem >= 64) ? ~0ull : ((1ull << cnt_rem) - 1ull);
            bool exhausted = ((vm & full) != full) || (e0 + 64 >= n);
            int nacc = nacc0;
            u64 amask = 0ull;
            for (int el = 0; el < cnt_rem; ++el) {
                if (nacc >= MAXDET) break;
                if (!((vm >> el) & 1ull)) break;
                if (!((sup_run >> el) & 1ull)) {
                    amask |= (1ull << el);
                    sup_run |= __shfl(m, el, 64);
                    ++nacc;
                }
            }
            if ((amask >> lane) & 1ull) {
                int slot = nacc0 + (int)__popcll(amask & ((1ull << lane) - 1ull));
                s_ax1[slot] = x1; s_ay1[slot] = y1;
                s_ax2[slot] = x2; s_ay2[slot] = y2;
                s_aar[slot] = ar;
                s_accE[slot] = e;
            }
            if (lane == 0) {
                s_nacc = nacc;
                if (nacc >= MAXDET || exhausted) s_done = 1;
            }
        }
        __syncthreads();
        if (s_done) break;
    }

    if (tid < MAXDET) {
        const int* ts = tsizes + b * 2;
        float th = (float)ts[0], tw = (float)ts[1];
        int d = tid;
        bool good = d < s_nacc;
        float sc = 0.0f, lb = -1.0f, gd = 0.0f;
        float ox1 = 0.f, oy1 = 0.f, ox2 = 0.f, oy2 = 0.f;
        if (good) {
            u64 pk = s_list[s_accE[d]];
            u32 key = (u32)(pk >> 32);
            u32 idx = ~((u32)pk);
            u32 qq = idx / CN, cc = idx - qq * CN;
            float L = fkey_inv(key);
            sc = 1.0f / (1.0f + expf(-L));
            lb = (float)cc;
            gd = 1.0f;
            ox1 = s_xyxy[qq][0] * tw;
            oy1 = s_xyxy[qq][1] * th;
            ox2 = s_xyxy[qq][2] * tw;
            oy2 = s_xyxy[qq][3] * th;
        }
        out[b * MAXDET + d] = sc;
        out[BIMG * MAXDET + b * MAXDET + d] = lb;
        float* ob = out + 2 * BIMG * MAXDET + (size_t)(b * MAXDET + d) * 4;
        ob[0] = ox1; ob[1] = oy1; ob[2] = ox2; ob[3] = oy2;
        out[2 * BIMG * MAXDET + BIMG * MAXDET * 4 + b * MAXDET + d] = gd;
    }
}

extern "C" void kernel_launch(void* const* d_in, const int* in_sizes, int n_in,
                              void* d_out, int out_size, void* d_ws, size_t ws_size,
                              hipStream_t stream) {
    (void)in_sizes; (void)n_in; (void)out_size;
    const float* logits = (const float*)d_in[0];
    const float* boxes  = (const float*)d_in[1];
    const int*   tsizes = (const int*)d_in[2];
    float* out = (float*)d_out;

    if (ws_size >= (size_t)WS_NEEDED) {
        char* ws = (char*)d_ws;
        u32* gcnt  = (u32*)(ws + WS_GCNT);
        u32* badbm = (u32*)(ws + WS_BADBM);
        u64* gseg  = (u64*)(ws + WS_GSEG);
        k_scan<<<BIMG * NSEG, 256, 0, stream>>>(logits, badbm, gcnt, gseg);
        k_main<<<BIMG, 512, 0, stream>>>(boxes, tsizes, badbm, gcnt, gseg, out);
    } else {
        ov_post<<<BIMG, NTHREADS, 0, stream>>>(logits, boxes, tsizes, out);
    }
}